// Round 10
// baseline (353.080 us; speedup 1.0000x reference)
//
#include <hip/hip_runtime.h>
#include <stdint.h>

typedef unsigned short u16;
typedef unsigned int   u32;
typedef __bf16 bf16x8 __attribute__((ext_vector_type(8)));
typedef float  f32x4  __attribute__((ext_vector_type(4)));
typedef u32    u32x4  __attribute__((ext_vector_type(4)));
typedef u32    u32x2  __attribute__((ext_vector_type(2)));

#define B_SZ  2
#define S_LEN 2048
#define NH    16
#define HD    64
#define DIM   1024
#define FF    4096
#define T_LEN 3072
#define PREV  1024
#define MROWS (B_SZ * S_LEN) /* 4096 */
#define LOG2E 1.44269504f

#define MFMA16 __builtin_amdgcn_mfma_f32_16x16x32_bf16

__device__ __forceinline__ u16 f2bf(float f) {
  u32 u = __builtin_bit_cast(u32, f);
  u32 r = u + 0x7FFFu + ((u >> 16) & 1u);
  return (u16)(r >> 16);
}
__device__ __forceinline__ float bf2f(u16 h) {
  u32 u = ((u32)h) << 16;
  return __builtin_bit_cast(float, u);
}
__device__ __forceinline__ u32 cvtpk(float lo, float hi) {
  u32 r;
  asm("v_cvt_pk_bf16_f32 %0, %1, %2" : "=v"(r) : "v"(lo), "v"(hi));
  return r;
}

// async global->LDS, 16B per lane. LDS dest must be wave-uniform base + lane*16.
__device__ __forceinline__ void gl_lds16(const void* g, void* l) {
  __builtin_amdgcn_global_load_lds(
      (const __attribute__((address_space(1))) u32*)g,
      (__attribute__((address_space(3))) u32*)l, 16, 0, 0);
}

#define GFENCE() asm volatile("" ::: "memory")
#define BARF()                         \
  do {                                 \
    GFENCE();                          \
    __builtin_amdgcn_s_barrier();      \
    GFENCE();                          \
  } while (0)
#define LGKM0()                                          \
  do {                                                   \
    asm volatile("s_waitcnt lgkmcnt(0)" ::: "memory");   \
    __builtin_amdgcn_sched_barrier(0);                   \
  } while (0)

// ---------------- ALL weight/bias conversion in ONE launch ----------------
__global__ __launch_bounds__(256) void cvt_all_kernel(
    const float* __restrict__ wq, const float* __restrict__ wk,
    const float* __restrict__ wv, const float* __restrict__ wg,
    const float* __restrict__ wval, const float* __restrict__ wo,
    const float* __restrict__ wp, const float* __restrict__ bq,
    const float* __restrict__ bk, const float* __restrict__ bv,
    const float* __restrict__ bg, const float* __restrict__ bval,
    u16* __restrict__ wqkv_bf, u16* __restrict__ wgv_bf,
    u16* __restrict__ wo_bf, u16* __restrict__ wp_bf,
    float* __restrict__ bqkv, float* __restrict__ bgv) {
  long gid = (long)blockIdx.x * 256 + threadIdx.x;
  if (gid < 393216) {  // wqkv, K-unit XOR-preswizzled
    int i = (int)gid;
    const int seg = i >> 17;
    const int loc = i & 131071;
    const float* src = (seg == 0) ? wq : (seg == 1) ? wk : wv;
    int row = loc >> 7;
    int g = loc & 127;
    const float* s = &src[((long)row << 10) + g * 8];
    f32x4 a = *(const f32x4*)s;
    f32x4 b = *(const f32x4*)(s + 4);
    u32x4 o;
    o[0] = (u32)f2bf(a[0]) | ((u32)f2bf(a[1]) << 16);
    o[1] = (u32)f2bf(a[2]) | ((u32)f2bf(a[3]) << 16);
    o[2] = (u32)f2bf(b[0]) | ((u32)f2bf(b[1]) << 16);
    o[3] = (u32)f2bf(b[2]) | ((u32)f2bf(b[3]) << 16);
    const int gp = (g & ~7) | ((g & 7) ^ (row & 7));
    *(u32x4*)&wqkv_bf[((long)seg << 20) + ((long)row << 10) + gp * 8] = o;
    return;
  }
  gid -= 393216;
  if (gid < 524288) {  // wgv interleave + preswizzle
    int i = (int)gid;
    int j = i >> 7;
    int g = i & 127;
    const float* sg = &wg[((long)j << 10) + g * 8];
    const float* sv = &wval[((long)j << 10) + g * 8];
    f32x4 a = *(const f32x4*)sg;
    f32x4 b = *(const f32x4*)(sg + 4);
    u32x4 og;
    og[0] = (u32)f2bf(a[0]) | ((u32)f2bf(a[1]) << 16);
    og[1] = (u32)f2bf(a[2]) | ((u32)f2bf(a[3]) << 16);
    og[2] = (u32)f2bf(b[0]) | ((u32)f2bf(b[1]) << 16);
    og[3] = (u32)f2bf(b[2]) | ((u32)f2bf(b[3]) << 16);
    f32x4 c = *(const f32x4*)sv;
    f32x4 d = *(const f32x4*)(sv + 4);
    u32x4 ov;
    ov[0] = (u32)f2bf(c[0]) | ((u32)f2bf(c[1]) << 16);
    ov[1] = (u32)f2bf(c[2]) | ((u32)f2bf(c[3]) << 16);
    ov[2] = (u32)f2bf(d[0]) | ((u32)f2bf(d[1]) << 16);
    ov[3] = (u32)f2bf(d[2]) | ((u32)f2bf(d[3]) << 16);
    const int rg = 2 * j, rv = 2 * j + 1;
    const int gpg = (g & ~7) | ((g & 7) ^ (rg & 7));
    const int gpv = (g & ~7) | ((g & 7) ^ (rv & 7));
    *(u32x4*)&wgv_bf[((long)rg << 10) + gpg * 8] = og;
    *(u32x4*)&wgv_bf[((long)rv << 10) + gpv * 8] = ov;
    return;
  }
  gid -= 524288;
  if (gid < 131072) {  // wo linear
    int i = (int)gid;
    f32x4 a = *(const f32x4*)&wo[(long)i * 8];
    f32x4 b = *(const f32x4*)&wo[(long)i * 8 + 4];
    u32x4 o;
    o[0] = (u32)f2bf(a[0]) | ((u32)f2bf(a[1]) << 16);
    o[1] = (u32)f2bf(a[2]) | ((u32)f2bf(a[3]) << 16);
    o[2] = (u32)f2bf(b[0]) | ((u32)f2bf(b[1]) << 16);
    o[3] = (u32)f2bf(b[2]) | ((u32)f2bf(b[3]) << 16);
    *(u32x4*)&wo_bf[(long)i * 8] = o;
    return;
  }
  gid -= 131072;
  if (gid < 524288) {  // wp linear
    int i = (int)gid;
    f32x4 a = *(const f32x4*)&wp[(long)i * 8];
    f32x4 b = *(const f32x4*)&wp[(long)i * 8 + 4];
    u32x4 o;
    o[0] = (u32)f2bf(a[0]) | ((u32)f2bf(a[1]) << 16);
    o[1] = (u32)f2bf(a[2]) | ((u32)f2bf(a[3]) << 16);
    o[2] = (u32)f2bf(b[0]) | ((u32)f2bf(b[1]) << 16);
    o[3] = (u32)f2bf(b[2]) | ((u32)f2bf(b[3]) << 16);
    *(u32x4*)&wp_bf[(long)i * 8] = o;
    return;
  }
  gid -= 524288;
  {  // bias packs
    int i = (int)gid;
    if (i < 3 * DIM) {
      float v = (i < DIM) ? bq[i] : (i < 2 * DIM) ? bk[i - DIM] : bv[i - 2 * DIM];
      bqkv[i] = v;
    } else if (i < 3 * DIM + FF) {
      int j = i - 3 * DIM;
      bgv[2 * j] = bg[j];
      bgv[2 * j + 1] = bval[j];
    }
  }
}

// ---------------- RMSNorm: fp32 row -> bf16 row, K-unit XOR-preswizzled out ----------------
__global__ __launch_bounds__(256) void rmsnorm_kernel(const float* __restrict__ x,
                                                      const float* __restrict__ w,
                                                      u16* __restrict__ out) {
  const int row = blockIdx.x;
  const int tid = threadIdx.x;
  const long base = (long)row * DIM + tid * 4;
  f32x4 v = *(const f32x4*)&x[base];
  float ss = v[0] * v[0] + v[1] * v[1] + v[2] * v[2] + v[3] * v[3];
#pragma unroll
  for (int d = 1; d <= 32; d <<= 1) ss += __shfl_xor(ss, d, 64);
  __shared__ float red[4];
  if ((tid & 63) == 0) red[tid >> 6] = ss;
  __syncthreads();
  float tot = red[0] + red[1] + red[2] + red[3];
  const float sc = rsqrtf(tot * (1.f / (float)DIM) + 1e-6f);
  f32x4 wv4 = *(const f32x4*)&w[tid * 4];
  u32x2 o;
  o[0] = (u32)f2bf(v[0] * sc * wv4[0]) | ((u32)f2bf(v[1] * sc * wv4[1]) << 16);
  o[1] = (u32)f2bf(v[2] * sc * wv4[2]) | ((u32)f2bf(v[3] * sc * wv4[3]) << 16);
  const int u = tid >> 1, hf = tid & 1;
  const int up = (u & 0x78) | ((u & 7) ^ (row & 7));
  *(u32x2*)&out[(long)row * DIM + up * 8 + hf * 4] = o;
}

// ---------------- 256x256 GEMM, 4 fine phases / K-tile (T2+T3+T4+T5) ----------------
// ph0{read A0+B0 -> Q00} ph1{read B1 -> Q01} ph2{read A1 -> Q10}
// ph3{stage kt+2 (WAR-safe after ph2 lgkm-drain+barrier) || Q11 -> vmcnt(8) boundary}
template <int EPI>
__global__ __launch_bounds__(512, 2) void gemm256(const u16* __restrict__ A,
                                                  const u16* __restrict__ Bw,
                                                  const float* __restrict__ bias,
                                                  u16* __restrict__ out_bf,
                                                  int N, int K) {
  __shared__ __align__(16) u16 Ab[2][256 * 64];
  __shared__ __align__(16) u16 Bb[2][256 * 64];
  const int tid = threadIdx.x;
  const int lane = tid & 63;
  const int wid = tid >> 6;
  const int wm = wid >> 2, wn = wid & 3;
  const int l15 = lane & 15, lhi = lane >> 4;
  const int c7 = l15 & 7;
  const long m0 = (long)blockIdx.y * 256;
  const long n0 = (long)blockIdx.x * 256;
  const int NT = K >> 6;

  const int srow = tid >> 3;
  const int sunit = (tid & 7) * 8;
  const u16* agp = A + (m0 + srow) * K + sunit;
  const u16* bgp = Bw + (n0 + srow) * K + sunit;
  const int ldst = tid * 8;

  auto stageA = [&](int kt, int b) {
    const int k0 = kt << 6;
    u16* d = &Ab[b][0];
#pragma unroll
    for (int c = 0; c < 4; ++c)
      gl_lds16(agp + (long)(c * 64) * K + k0, d + c * 4096 + ldst);
  };
  auto stageB = [&](int kt, int b) {
    const int k0 = kt << 6;
    u16* d = &Bb[b][0];
#pragma unroll
    for (int c = 0; c < 4; ++c)
      gl_lds16(bgp + (long)(c * 64) * K + k0, d + c * 4096 + ldst);
  };

#define READ_A(arr, MH)                                                          \
  _Pragma("unroll") for (int m_ = 0; m_ < 4; ++m_) {                             \
    _Pragma("unroll") for (int ks_ = 0; ks_ < 2; ++ks_) {                        \
      arr[m_ * 2 + ks_] =                                                        \
          *(const bf16x8*)&Ac[(wm * 128 + (MH)*64 + m_ * 16 + l15) * 64 +        \
                              (((ks_ * 4 + lhi) ^ c7) * 8)];                     \
    }                                                                            \
  }
#define READ_B(arr, NH)                                                          \
  _Pragma("unroll") for (int n_ = 0; n_ < 2; ++n_) {                             \
    _Pragma("unroll") for (int ks_ = 0; ks_ < 2; ++ks_) {                        \
      arr[n_ * 2 + ks_] =                                                        \
          *(const bf16x8*)&Bc[(wn * 64 + (NH)*32 + n_ * 16 + l15) * 64 +         \
                              (((ks_ * 4 + lhi) ^ c7) * 8)];                     \
    }                                                                            \
  }
#define QUADX(Aarr, Barr, MH, NH)                                                \
  do {                                                                           \
    __builtin_amdgcn_s_setprio(1);                                               \
    _Pragma("unroll") for (int m_ = 0; m_ < 4; ++m_) {                           \
      _Pragma("unroll") for (int n_ = 0; n_ < 2; ++n_) {                         \
        acc[(MH)*4 + m_][(NH)*2 + n_] =                                          \
            MFMA16(Aarr[m_ * 2], Barr[n_ * 2],                                   \
                   acc[(MH)*4 + m_][(NH)*2 + n_], 0, 0, 0);                      \
        acc[(MH)*4 + m_][(NH)*2 + n_] =                                          \
            MFMA16(Aarr[m_ * 2 + 1], Barr[n_ * 2 + 1],                           \
                   acc[(MH)*4 + m_][(NH)*2 + n_], 0, 0, 0);                      \
      }                                                                          \
    }                                                                            \
    __builtin_amdgcn_s_setprio(0);                                               \
  } while (0)

  f32x4 acc[8][4] = {};

  // prologue: tiles 0,1 staged; wait tile 0 (tile 1 stays in flight)
  stageA(0, 0);
  stageB(0, 0);
  stageA(1, 1);
  stageB(1, 1);
  asm volatile("s_waitcnt vmcnt(8)" ::: "memory");
  __builtin_amdgcn_s_barrier();
  GFENCE();

  for (int kt = 0; kt < NT; ++kt) {
    const int b = kt & 1;
    const u16* Ac = &Ab[b][0];
    const u16* Bc = &Bb[b][0];
    bf16x8 Afr[8], Bf0[4], Bf1[4];
    // ph0: read A-half0 + B-half0 (12 ds_read), quad (0,0)
    READ_A(Afr, 0);
    READ_B(Bf0, 0);
    BARF();
    LGKM0();
    QUADX(Afr, Bf0, 0, 0);
    BARF();
    // ph1: read B-half1 (4 ds_read), quad (0,1)
    READ_B(Bf1, 1);
    BARF();
    LGKM0();
    QUADX(Afr, Bf1, 0, 1);
    BARF();
    // ph2: read A-half1 (8 ds_read, reg reuse), quad (1,0)
    READ_A(Afr, 1);
    BARF();
    LGKM0();
    QUADX(Afr, Bf0, 1, 0);
    BARF();
    // ph3: all buf-b reads drained (every wave did lgkmcnt(0) in ph2 before this
    // barrier) -> stage kt+2 into buf b; quad (1,1) overlaps the staging issue
    if (kt + 2 < NT) {
      stageA(kt + 2, b);
      stageB(kt + 2, b);
    }
    QUADX(Afr, Bf1, 1, 1);
    // boundary: tile kt+1 must be resident; keep kt+2 prefetch in flight
    if (kt + 1 < NT) {
      if (kt + 2 < NT)
        asm volatile("s_waitcnt vmcnt(8)" ::: "memory");
      else
        asm volatile("s_waitcnt vmcnt(0)" ::: "memory");
      __builtin_amdgcn_s_barrier();
      GFENCE();
    }
  }
#undef READ_A
#undef READ_B
#undef QUADX

#pragma unroll
  for (int mi = 0; mi < 8; ++mi) {
    const long row0 = m0 + wm * 128 + mi * 16 + lhi * 4;
#pragma unroll
    for (int ni = 0; ni < 4; ++ni) {
      const long col = n0 + wn * 64 + ni * 16 + l15;
      const float bb = bias[col];
#pragma unroll
      for (int r = 0; r < 4; ++r) {
        float v = acc[mi][ni][r] + bb;
        if (EPI == 2) {
          float other = __shfl_xor(v, 1, 64);
          if (!(l15 & 1)) {
            float s = v / (1.f + __expf(-v)) * other;  // silu(g)*v
            out_bf[(row0 + r) * (N >> 1) + (col >> 1)] = f2bf(s);
          }
        } else {
          out_bf[(row0 + r) * N + col] = f2bf(v);
        }
      }
    }
  }
}

// ---------------- 3-buffer GEMM (linear layouts) for skinny N ----------------
template <int EPI, int NB>
__global__ __launch_bounds__(256) void gemm_bt(const u16* __restrict__ A,
                                               const u16* __restrict__ Bw,
                                               const float* __restrict__ bias,
                                               const float* __restrict__ resid,
                                               u16* __restrict__ out_bf,
                                               float* __restrict__ out_f,
                                               int N, int K) {
  constexpr int BHALF = NB / 64;
  constexpr int NFR = NB / 32;
  constexpr int LPT = 2 + BHALF;
  __shared__ __align__(16) u16 As[3][128 * 32];
  __shared__ __align__(16) u16 Bs[3][NB * 32];
  const int tid = threadIdx.x;
  const int lane = tid & 63;
  const int wv = tid >> 6;
  const int wr = wv >> 1, wc = wv & 1;
  const long m0 = (long)blockIdx.y * 128;
  const long n0 = (long)blockIdx.x * NB;

  const int arow = tid >> 2;
  const int acol = (tid & 3) << 3;
  const u16* ag = A + (m0 + arow) * K + acol;
  const u16* bg = Bw + (n0 + arow) * K + acol;
  const long hK = (long)64 * K;

  f32x4 acc[4][NFR] = {};
  const int l15 = lane & 15;
  const int lhi = lane >> 4;
  const int aoff0 = (wr * 64 + l15) * 32 + lhi * 8;
  const int boff0 = (wc * (NB / 2) + l15) * 32 + lhi * 8;
  const int nk = K >> 5;

  auto stage = [&](int t, int buf) {
    const int k0 = t << 5;
    gl_lds16(ag + k0, &As[buf][tid * 8]);
    gl_lds16(ag + k0 + hK, &As[buf][2048 + tid * 8]);
    gl_lds16(bg + k0, &Bs[buf][tid * 8]);
    if (BHALF == 2) gl_lds16(bg + k0 + hK, &Bs[buf][2048 + tid * 8]);
  };

  stage(0, 0);
  stage(1, 1);
  asm volatile("s_waitcnt vmcnt(%0)" ::"n"(LPT) : "memory");
  __builtin_amdgcn_s_barrier();
  GFENCE();

  for (int t = 0; t < nk; ++t) {
    const int cb = t % 3;
    if (t + 2 < nk) stage(t + 2, (t + 2) % 3);
    bf16x8 af[4], bfr[NFR];
#pragma unroll
    for (int i = 0; i < 4; ++i) af[i] = *(const bf16x8*)&As[cb][aoff0 + i * 16 * 32];
#pragma unroll
    for (int j = 0; j < NFR; ++j) bfr[j] = *(const bf16x8*)&Bs[cb][boff0 + j * 16 * 32];
    __builtin_amdgcn_s_setprio(1);
#pragma unroll
    for (int i = 0; i < 4; ++i)
#pragma unroll
      for (int j = 0; j < NFR; ++j)
        acc[i][j] = MFMA16(af[i], bfr[j], acc[i][j], 0, 0, 0);
    __builtin_amdgcn_s_setprio(0);
    if (t + 2 < nk) {
      asm volatile("s_waitcnt vmcnt(%0)" ::"n"(LPT) : "memory");
      __builtin_amdgcn_s_barrier();
      GFENCE();
    } else if (t + 1 < nk) {
      asm volatile("s_waitcnt vmcnt(0)" ::: "memory");
      __builtin_amdgcn_s_barrier();
      GFENCE();
    }
  }

#pragma unroll
  for (int i = 0; i < 4; ++i) {
    const long row0 = m0 + wr * 64 + i * 16 + lhi * 4;
#pragma unroll
    for (int j = 0; j < NFR; ++j) {
      const long col = n0 + wc * (NB / 2) + j * 16 + l15;
      const float bb = bias[col];
#pragma unroll
      for (int r = 0; r < 4; ++r) {
        const long idx = (row0 + r) * N + col;
        float v = acc[i][j][r] + bb;
        if (EPI == 0) out_bf[idx] = f2bf(v);
        else          out_f[idx] = resid[idx] + v;
      }
    }
  }
}

// ---------------- fused RoPE(Q), RoPE(K)+concat, V-transpose+concat ----------------
// blocks [0,2048): Q; [2048,5120): K; [5120,8192): Vt
__global__ __launch_bounds__(256) void rope_all_kernel(const u16* __restrict__ qkv,
                                                       const float* __restrict__ cache_k,
                                                       const float* __restrict__ cache_v,
                                                       const float* __restrict__ cosT,
                                                       const float* __restrict__ sinT,
                                                       u16* __restrict__ Q,
                                                       u16* __restrict__ Kall,
                                                       u16* __restrict__ Vtg) {
  const int blk = blockIdx.x;
  if (blk < 2048) {
    int idx = blk * 256 + threadIdx.x;  // B*H*S*8 = 524288 units of 8 elems
    int u = idx & 7;
    int s = (idx >> 3) & (S_LEN - 1);
    int bh = idx >> 14;
    int b = bh >> 4, h = bh & 15;
    int pos = PREV + s;
    const float SC = 0.125f * LOG2E;
    const u16* src = qkv + ((long)(b * S_LEN + s)) * (3 * DIM) + h * HD + u * 8;
    u32x4 d = *(const u32x4*)src;
    f32x4 cv = *(const f32x4*)&cosT[(long)pos * 32 + u * 4];
    f32x4 sv = *(const f32x4*)&sinT[(long)pos * 32 + u * 4];
    u32x4 o;
#pragma unroll
    for (int p = 0; p < 4; ++p) {
      float x0 = bf2f((u16)(d[p] & 0xffff));
      float x1 = bf2f((u16)(d[p] >> 16));
      float y0 = (x0 * cv[p] - x1 * sv[p]) * SC;
      float y1 = (x0 * sv[p] + x1 * cv[p]) * SC;
      o[p] = (u32)f2bf(y0) | ((u32)f2bf(y1) << 16);
    }
    *(u32x4*)&Q[((long)bh * S_LEN + s) * HD + u * 8] = o;
  } else if (blk < 5120) {
    int idx = (blk - 2048) * 256 + threadIdx.x;  // B*H*T*8 = 786432
    int u = idx & 7;
    int t2 = idx >> 3;
    int j = t2 % T_LEN;
    int bh = t2 / T_LEN;
    int b = bh >> 4, h = bh & 15;
    float e[8];
    if (j < PREV) {
      const float* src = cache_k + ((long)bh * PREV + j) * HD + u * 8;
      f32x4 a = *(const f32x4*)src;
      f32x4 c = *(const f32x4*)(src + 4);
      e[0] = a[0]; e[1] = a[1]; e[2] = a[2]; e[3] = a[3];
      e[4] = c[0]; e[5] = c[1]; e[6] = c[2]; e[7] = c[3];
    } else {
      const u16* src = qkv + ((long)(b * S_LEN + (j - PREV))) * (3 * DIM) + DIM + h * HD + u * 8;
      u32x4 d = *(const u32x4*)src;
#pragma unroll
      for (int p = 0; p < 4; ++p) {
        e[2 * p] = bf2f((u16)(d[p] & 0xffff));
        e[2 * p + 1] = bf2f((u16)(d[p] >> 16));
      }
    }
    f32x4 cv = *(const f32x4*)&cosT[(long)j * 32 + u * 4];
    f32x4 sv = *(const f32x4*)&sinT[(long)j * 32 + u * 4];
    u32x4 o;
#pragma unroll
    for (int p = 0; p < 4; ++p) {
      float y0 = e[2 * p] * cv[p] - e[2 * p + 1] * sv[p];
      float y1 = e[2 * p] * sv[p] + e[2 * p + 1] * cv[p];
      o[p] = (u32)f2bf(y0) | ((u32)f2bf(y1) << 16);
    }
    *(u32x4*)&Kall[((long)bh * T_LEN + j) * HD + (u ^ (j & 7)) * 8] = o;
  } else {
    int idx = (blk - 5120) * 256 + threadIdx.x;  // 32 * 384 * 64 = 786432
    int hd = idx & 63;
    int t2 = idx >> 6;
    int kb = t2 % 384;  // 8-key block
    int bh = t2 / 384;
    int b = bh >> 4, h = bh & 15;
    int key0 = kb * 8;
    u16 vals[8];
    if (key0 < PREV) {
#pragma unroll
      for (int i = 0; i < 8; ++i)
        vals[i] = f2bf(cache_v[((long)bh * PREV + key0 + i) * HD + hd]);
    } else {
#pragma unroll
      for (int i = 0; i < 8; ++i)
        vals[i] = qkv[((long)(b * S_LEN + key0 + i - PREV)) * (3 * DIM) + 2 * DIM + h * HD + hd];
    }
    u32x4 o;
#pragma unroll
    for (int p = 0; p < 4; ++p)
      o[p] = (u32)vals[2 * p] | ((u32)vals[2 * p + 1] << 16);
    const int span = kb >> 3;
    const int u = (kb & 7) ^ (hd & 7);
    *(u32x4*)&Vtg[((long)bh * HD + hd) * T_LEN + span * 64 + u * 8] = o;
  }
}

// ---------------- flash attention: paired dual-Q blocks, shared KV sweep ----------------
__global__ __launch_bounds__(256, 2) void attn_kernel(const u16* __restrict__ Q,
                                                      const u16* __restrict__ Kg,
                                                      const u16* __restrict__ Vtg,
                                                      u16* __restrict__ ctx, float slope2) {
  __shared__ __align__(16) u16 Ks[2][64 * 64];     // [key][d], swizzled
  __shared__ __align__(16) u16 Vs[2][64 * 64];     // [hd][key], swizzled
  __shared__ __align__(16) u16 Ps[2][4][16 * 64];  // per-qset per-wave P, swizzled

  const int tid = threadIdx.x;
  const int lane = tid & 63;
  const int wv = tid >> 6;
  const int l15 = lane & 15;
  const int lhi = lane >> 4;
  const int c7 = l15 & 7;
  const int bh = blockIdx.x;
  const int p = blockIdx.y;            // pair index 0..15
  const int b = bh >> 4, h = bh & 15;
  const int qA0 = p * 64;
  const int qB0 = (31 - p) * 64;
  const int ntA = 17 + p;              // (PREV + qA0 + 64) >> 6
  const int ntB = 48 - p;              // ntA + ntB = 65

  const long qrowA = (long)bh * S_LEN + qA0 + wv * 16 + l15;
  const long qrowB = (long)bh * S_LEN + qB0 + wv * 16 + l15;
  bf16x8 aqA0 = *(const bf16x8*)&Q[qrowA * HD + lhi * 8];
  bf16x8 aqA1 = *(const bf16x8*)&Q[qrowA * HD + 32 + lhi * 8];
  bf16x8 aqB0 = *(const bf16x8*)&Q[qrowB * HD + lhi * 8];
  bf16x8 aqB1 = *(const bf16x8*)&Q[qrowB * HD + 32 + lhi * 8];

  const long kgb = (long)bh * T_LEN * HD;  // K: [key][64]
  const long vgb = (long)bh * HD * T_LEN;  // Vt: [hd][T]
  const int srow = tid >> 3;               // staging row 0..31
  const int sunit = (tid & 7) * 8;

  const u16* kst = Kg + kgb + (long)srow * HD + sunit;     // +64*HD per tile
  const u16* vst = Vtg + vgb + (long)srow * T_LEN + sunit; // +64 per tile

  // prologue: stage tile 0
  gl_lds16(kst, &Ks[0][tid * 8]);
  gl_lds16(kst + 32 * HD, &Ks[0][2048 + tid * 8]);
  gl_lds16(vst, &Vs[0][tid * 8]);
  gl_lds16(vst + (long)32 * T_LEN, &Vs[0][2048 + tid * 8]);
  kst += 64 * HD;
  vst += 64;
  __syncthreads();

  f32x4 oA[4] = {}, oB[4] = {};
  f32x4 lrunA = {0.f, 0.f, 0.f, 0.f}, lrunB = {0.f, 0.f, 0.f, 0.f};
  float mrunA = -1e30f, mrunB = -1e30f;
  const int qq = wv * 16 + l15;  // local q (mask threshold, same layout both q-sets)

  f32x4 be[4];  // per-thread bias constants slope*(jf*16+4*lhi+r)
#pragma unroll
  for (int jf = 0; jf < 4; ++jf)
#pragma unroll
    for (int r = 0; r < 4; ++r)
      be[jf][r] = slope2 * (float)(jf * 16 + 4 * lhi + r);
  const float bmax = slope2 * 63.f;

  bf16x8 vones;
#pragma unroll
  for (int e = 0; e < 8; ++e) vones[e] = (__bf16)1.0f;

  float ktf = 0.f;
  const float kstep = slope2 * 64.f;

  // softmax + PV for one q-set (separate P buffer per q-set)
  auto process = [&](f32x4 (&sf)[4], bool maskNow, f32x4 (&o)[4], f32x4& lrun,
                     float& mrun, bf16x8 (&vf)[8], u16* Pw) {
    if (maskNow) {
#pragma unroll
      for (int jf = 0; jf < 4; ++jf)
#pragma unroll
        for (int r = 0; r < 4; ++r)
          if (jf * 16 + 4 * lhi + r > qq) sf[jf][r] = -1e30f;
    }
    float h0 = fmaxf(fmaxf(sf[0][0], sf[0][1]), fmaxf(sf[0][2], sf[0][3]));
    float h1 = fmaxf(fmaxf(sf[1][0], sf[1][1]), fmaxf(sf[1][2], sf[1][3]));
    float h2 = fmaxf(fmaxf(sf[2][0], sf[2][1]), fmaxf(sf[2][2], sf[2][3]));
    float h3 = fmaxf(fmaxf(sf[3][0], sf[3][1]), fmaxf(sf[3][2], sf[3][3]));
    float pm = fmaxf(fmaxf(h0, h1), fmaxf(h2, h3));
    pm = fmaxf(pm, __shfl_xor(pm, 16, 64));
    pm = fmaxf(pm, __shfl_xor(pm, 32, 64));
    const float pmax_abs = pm + ktf + bmax;

    if (!__all(pmax_abs - mrun <= 8.f)) {
      const float mnew = fmaxf(mrun, pmax_abs);
      const float scl = exp2f(mrun - mnew);
      mrun = mnew;
#pragma unroll
      for (int r = 0; r < 4; ++r) {
        const float sr = __shfl(scl, 4 * lhi + r, 64);
        lrun[r] *= sr;
#pragma unroll
        for (int hf = 0; hf < 4; ++hf) o[hf][r] *= sr;
      }
    }
    const float meff = mrun - ktf;

#pragma unroll
    for (int jf = 0; jf < 4; ++jf) {
      f32x4 pp;
#pragma unroll
      for (int r = 0; r < 4; ++r)
        pp[r] = exp2f(sf[jf][r] + (be[jf][r] - meff));
      u32x2 pw2;
      pw2[0] = cvtpk(pp[0], pp[1]);
      pw2[1] = cvtpk(pp[2], pp[3]);
      const int u = (2 * jf + (lhi >> 1)) ^ c7;
      *(u32x2*)&Pw[l15 * 64 + u * 8 + (lhi & 1) * 4] = pw2;
    }

    bf16x8 pa0 = *(const bf16x8*)&Pw[l15 * 64 + ((lhi ^ c7) * 8)];
    bf16x8 pa1 = *(const bf16x8*)&Pw[l15 * 64 + (((4 + lhi) ^ c7) * 8)];
    f32x4 psum = {};
    __builtin_amdgcn_s_setprio(1);
    psum = MFMA16(pa0, vones, psum, 0, 0, 0);
    psum = MFMA16(pa1, vones, psum, 0, 0, 0);
#pragma unroll
    for (int hf = 0; hf < 4; ++hf) {
      o[hf] = MFMA16(pa0, vf[2 * hf], o[hf], 0, 0, 0);
      o[hf] = MFMA16(pa1, vf[2 * hf + 1], o[hf], 0, 0, 0);
    }
    __builtin_amdgcn_s_setprio(0);
    lrun += psum;
  };

  for (int t = 0; t < ntB; ++t) {
    const int cur = t & 1, nxt = cur ^ 1;
    const bool lastStage = (t + 1 == ntB);
    if (!lastStage) {
      gl_lds16(kst, &Ks[nxt][tid * 8]);
      gl_lds16(kst + 32 * HD, &Ks[nxt][2048 + tid * 8]);
      gl_lds16(vst, &Vs[nxt][tid * 8]);
      gl_lds16(vst + (long)32 * T_LEN, &Vs[nxt][2048 + tid * 8]);
      kst += 64 * HD;
      vst += 64;
    }
    const bool actA = (t < ntA);

    // K fragments once, shared by both q-sets
    bf16x8 kf[8];
#pragma unroll
    for (int jf = 0; jf < 4; ++jf) {
      const int krow = jf * 16 + l15;
      kf[2 * jf] = *(const bf16x8*)&Ks[cur][krow * 64 + ((lhi ^ c7) * 8)];
      kf[2 * jf + 1] = *(const bf16x8*)&Ks[cur][krow * 64 + (((4 + lhi) ^ c7) * 8)];
    }
    // V fragments once, shared by both q-sets
    bf16x8 vf[8];
#pragma unroll
    for (int hf = 0; hf < 4; ++hf) {
      const int vrow = hf * 16 + l15;
      vf[2 * hf] = *(const bf16x8*)&Vs[cur][vrow * 64 + ((lhi ^ c7) * 8)];
      vf[2 * hf + 1] = *(const bf16x8*)&Vs[cur][vrow * 64 + (((4 + lhi) ^ c7) * 8)];
    }

    // QK^T for both q-sets
    f32x4 sB[4], sA[4];
    __builtin_amdgcn_s_setprio(1);
#pragma unroll
    for (int jf = 0; jf < 4; ++jf) {
      f32x4 s = {};
      s = MFMA16(kf[2 * jf], aqB0, s, 0, 0, 0);
      s = MFMA16(kf[2 * jf + 1], aqB1, s, 0, 0, 0);
      sB[jf] = s;
    }
    __builtin_amdgcn_s_setprio(0);
    if (actA) {
      __builtin_amdgcn_s_setprio(1);
#pragma unroll
      for (int jf = 0; jf < 4; ++jf) {
        f32x4 s = {};
        s = MFMA16(kf[2 * jf], aqA0, s, 0, 0, 0);
        s = MFMA16(kf[2 * jf + 1], aqA1, s, 0, 0, 0);
        sA[jf] = s;
      }
      __builtin_amdgcn_s_setprio(0);
    }

    process(sB, t == ntB - 1, oB, lrunB, mrunB, vf, &Ps[0][wv][0]);
    if (actA) process(sA, t == ntA - 1, oA, lrunA, mrunA, vf, &Ps[1][wv][0]);

    ktf += kstep;
    if (!lastStage) __syncthreads();
  }

  // epilogue: rows q_local = 4*lhi + r; cols hd = hf*16 + l15
#pragma unroll
  for (int r = 0; r < 4; ++r) {
    const float invA = 1.f / lrunA[r];
    const float invB = 1.f / lrunB[r];
    const long rowA = (long)b * S_LEN + qA0 + wv * 16 + 4 * lhi + r;
    const long rowB = (long)b * S_LEN + qB0 + wv * 16 + 4 * lhi + r;
#pragma unroll
    for (int hf = 0; hf < 4; ++hf) {
      ctx[rowA * DIM + h * HD + hf * 16 + l15] = f2bf(oA[hf][r] * invA);
      ctx[rowB * DIM + h * HD + hf * 16 + l15] = f2bf(oB[hf][r] * invB);
    }
  }
}

// ---------------------------------------------------------------------------
extern "C" void kernel_launch(void* const* d_in, const int* in_sizes, int n_in,
                              void* d_out, int out_size, void* d_ws, size_t ws_size,
                              hipStream_t stream) {
  (void)in_sizes; (void)n_in; (void)out_size; (void)ws_size;
  const float* x       = (const float*)d_in[0];
  const float* cache_k = (const float*)d_in[1];
  const float* cache_v = (const float*)d_in[2];
  const float* cosT    = (const float*)d_in[3];
  const float* sinT    = (const float*)d_in[4];
  const float* attn_w  = (const float*)d_in[5];
  const float* ffn_w   = (const float*)d_in[6];
  const float* wq      = (const float*)d_in[7];
  const float* bq      = (const float*)d_in[8];
  const float* wk      = (const float*)d_in[9];
  const float* bk      = (const float*)d_in[10];
  const float* wv_     = (const float*)d_in[11];
  const float* bv      = (const float*)d_in[12];
  const float* wo      = (const float*)d_in[13];
  const float* bo      = (const float*)d_in[14];
  const float* wg      = (const float*)d_in[15];
  const float* bg      = (const float*)d_in[16];
  const float* wval    = (const float*)d_in[17];
  const float* bval    = (const float*)d_in[18];
  const float* wp      = (const float*)d_in[19];
  const float* bp      = (const float*)d_in[20];
  float* out = (float*)d_out;

  char* w = (char*)d_ws;
  size_t off = 0;
  auto alloc = [&](size_t bytes) -> char* {
    char* p = w + off;
    off += (bytes + 255) & ~(size_t)255;
    return p;
  };
  // permanent
  u16*   wqkv_bf  = (u16*)alloc((size_t)3 * DIM * DIM * 2);  // preswizzled
  u16*   wo_bf    = (u16*)alloc((size_t)DIM * DIM * 2);      // linear
  u16*   wgv_bf   = (u16*)alloc((size_t)2 * FF * DIM * 2);   // interleaved+preswizzled
  u16*   wproj_bf = (u16*)alloc((size_t)DIM * FF * 2);       // linear
  float* bqkv     = (float*)alloc((size_t)3 * DIM * 4);
  float* bgv      = (float*)alloc((size_t)2 * FF * 4);       // interleaved
  float* x2       = (float*)alloc((size_t)MROWS * DIM * 4);
  // arena with lifetime-based aliasing
  char* AR = alloc((size_t)117440512);
  u16* qkv   = (u16*)(AR + 0);          // [4096][3072]   live: qkv gemm -> rope/build
  u16* Qb    = (u16*)(AR + 25165824);   // [32][2048][64] live: rope -> attn
  u16* Kb    = (u16*)(AR + 33554432);   // [32][3072][64]
  u16* Vtg   = (u16*)(AR + 46137344);   // [32][64][3072] transposed V
  u16* h1    = (u16*)(AR + 58720256);   // [4096][1024]   preswizzled (qkv gemm A)
  u16* ctx   = (u16*)(AR + 0);          // [4096][1024]   linear (aliases dead qkv)
  u16* h2    = (u16*)(AR + 8388608);    // [4096][1024]   preswizzled (gv gemm A)
  u16* gated = (u16*)(AR + 16777216);   // [4096][4096]   linear

  // 1) ALL weight + bias conversion in one launch
  cvt_all_kernel<<<6172, 256, 0, stream>>>(wq, wk, wv_, wg, wval, wo, wp,
                                           bq, bk, bv, bg, bval,
                                           wqkv_bf, wgv_bf, wo_bf, wproj_bf,
                                           bqkv, bgv);

  // 2) attn rmsnorm (swizzled out), fused QKV 256-gemm
  rmsnorm_kernel<<<MROWS, 256, 0, stream>>>(x, attn_w, h1);
  gemm256<0><<<dim3(12, 16), 512, 0, stream>>>(h1, wqkv_bf, bqkv, qkv, 3 * DIM, DIM);
  // 3) fused rope + cache concat (1 launch)
  rope_all_kernel<<<8192, 256, 0, stream>>>(qkv, cache_k, cache_v, cosT, sinT,
                                            Qb, Kb, Vtg);
  // 4) attention: paired dual-Q blocks
  attn_kernel<<<dim3(B_SZ * NH, 16), 256, 0, stream>>>(
      Qb, Kb, Vtg, ctx, (2.0f / (float)(T_LEN - 1)) * LOG2E);
  // 5) o-proj + residual (fp32), skinny tile
  gemm_bt<1, 64><<<dim3(16, 32), 256, 0, stream>>>(ctx, wo_bf, bo, x, nullptr, x2,
                                                   DIM, DIM);
  // 6) ffn rmsnorm (swizzled out), gate+value 256-gemm w/ silu epilogue, proj + residual
  rmsnorm_kernel<<<MROWS, 256, 0, stream>>>(x2, ffn_w, h2);
  gemm256<2><<<dim3(32, 16), 512, 0, stream>>>(h2, wgv_bf, bgv, gated, 2 * FF, DIM);
  gemm_bt<1, 64><<<dim3(16, 32), 256, 0, stream>>>(gated, wproj_bf, bp, x2, nullptr, out,
                                                   DIM, FF);
}

// Round 11
// 352.194 us; speedup vs baseline: 1.0025x; 1.0025x over previous
//
#include <hip/hip_runtime.h>
#include <stdint.h>

typedef unsigned short u16;
typedef unsigned int   u32;
typedef __bf16 bf16x8 __attribute__((ext_vector_type(8)));
typedef float  f32x4  __attribute__((ext_vector_type(4)));
typedef u32    u32x4  __attribute__((ext_vector_type(4)));
typedef u32    u32x2  __attribute__((ext_vector_type(2)));

#define B_SZ  2
#define S_LEN 2048
#define NH    16
#define HD    64
#define DIM   1024
#define FF    4096
#define T_LEN 3072
#define PREV  1024
#define MROWS (B_SZ * S_LEN) /* 4096 */
#define LOG2E 1.44269504f

#define MFMA16 __builtin_amdgcn_mfma_f32_16x16x32_bf16

__device__ __forceinline__ u16 f2bf(float f) {
  u32 u = __builtin_bit_cast(u32, f);
  u32 r = u + 0x7FFFu + ((u >> 16) & 1u);
  return (u16)(r >> 16);
}
__device__ __forceinline__ float bf2f(u16 h) {
  u32 u = ((u32)h) << 16;
  return __builtin_bit_cast(float, u);
}
__device__ __forceinline__ u32 cvtpk(float lo, float hi) {
  u32 r;
  asm("v_cvt_pk_bf16_f32 %0, %1, %2" : "=v"(r) : "v"(lo), "v"(hi));
  return r;
}

// async global->LDS, 16B per lane. LDS dest must be wave-uniform base + lane*16.
__device__ __forceinline__ void gl_lds16(const void* g, void* l) {
  __builtin_amdgcn_global_load_lds(
      (const __attribute__((address_space(1))) u32*)g,
      (__attribute__((address_space(3))) u32*)l, 16, 0, 0);
}

#define GFENCE() asm volatile("" ::: "memory")
#define BARF()                         \
  do {                                 \
    GFENCE();                          \
    __builtin_amdgcn_s_barrier();      \
    GFENCE();                          \
  } while (0)
#define LGKM0()                                          \
  do {                                                   \
    asm volatile("s_waitcnt lgkmcnt(0)" ::: "memory");   \
    __builtin_amdgcn_sched_barrier(0);                   \
  } while (0)

// ---------------- ALL weight/bias conversion in ONE launch ----------------
__global__ __launch_bounds__(256) void cvt_all_kernel(
    const float* __restrict__ wq, const float* __restrict__ wk,
    const float* __restrict__ wv, const float* __restrict__ wg,
    const float* __restrict__ wval, const float* __restrict__ wo,
    const float* __restrict__ wp, const float* __restrict__ bq,
    const float* __restrict__ bk, const float* __restrict__ bv,
    const float* __restrict__ bg, const float* __restrict__ bval,
    u16* __restrict__ wqkv_bf, u16* __restrict__ wgv_bf,
    u16* __restrict__ wo_bf, u16* __restrict__ wp_bf,
    float* __restrict__ bqkv, float* __restrict__ bgv) {
  long gid = (long)blockIdx.x * 256 + threadIdx.x;
  if (gid < 393216) {  // wqkv, K-unit XOR-preswizzled
    int i = (int)gid;
    const int seg = i >> 17;
    const int loc = i & 131071;
    const float* src = (seg == 0) ? wq : (seg == 1) ? wk : wv;
    int row = loc >> 7;
    int g = loc & 127;
    const float* s = &src[((long)row << 10) + g * 8];
    f32x4 a = *(const f32x4*)s;
    f32x4 b = *(const f32x4*)(s + 4);
    u32x4 o;
    o[0] = (u32)f2bf(a[0]) | ((u32)f2bf(a[1]) << 16);
    o[1] = (u32)f2bf(a[2]) | ((u32)f2bf(a[3]) << 16);
    o[2] = (u32)f2bf(b[0]) | ((u32)f2bf(b[1]) << 16);
    o[3] = (u32)f2bf(b[2]) | ((u32)f2bf(b[3]) << 16);
    const int gp = (g & ~7) | ((g & 7) ^ (row & 7));
    *(u32x4*)&wqkv_bf[((long)seg << 20) + ((long)row << 10) + gp * 8] = o;
    return;
  }
  gid -= 393216;
  if (gid < 524288) {  // wgv interleave + preswizzle
    int i = (int)gid;
    int j = i >> 7;
    int g = i & 127;
    const float* sg = &wg[((long)j << 10) + g * 8];
    const float* sv = &wval[((long)j << 10) + g * 8];
    f32x4 a = *(const f32x4*)sg;
    f32x4 b = *(const f32x4*)(sg + 4);
    u32x4 og;
    og[0] = (u32)f2bf(a[0]) | ((u32)f2bf(a[1]) << 16);
    og[1] = (u32)f2bf(a[2]) | ((u32)f2bf(a[3]) << 16);
    og[2] = (u32)f2bf(b[0]) | ((u32)f2bf(b[1]) << 16);
    og[3] = (u32)f2bf(b[2]) | ((u32)f2bf(b[3]) << 16);
    f32x4 c = *(const f32x4*)sv;
    f32x4 d = *(const f32x4*)(sv + 4);
    u32x4 ov;
    ov[0] = (u32)f2bf(c[0]) | ((u32)f2bf(c[1]) << 16);
    ov[1] = (u32)f2bf(c[2]) | ((u32)f2bf(c[3]) << 16);
    ov[2] = (u32)f2bf(d[0]) | ((u32)f2bf(d[1]) << 16);
    ov[3] = (u32)f2bf(d[2]) | ((u32)f2bf(d[3]) << 16);
    const int rg = 2 * j, rv = 2 * j + 1;
    const int gpg = (g & ~7) | ((g & 7) ^ (rg & 7));
    const int gpv = (g & ~7) | ((g & 7) ^ (rv & 7));
    *(u32x4*)&wgv_bf[((long)rg << 10) + gpg * 8] = og;
    *(u32x4*)&wgv_bf[((long)rv << 10) + gpv * 8] = ov;
    return;
  }
  gid -= 524288;
  if (gid < 131072) {  // wo linear
    int i = (int)gid;
    f32x4 a = *(const f32x4*)&wo[(long)i * 8];
    f32x4 b = *(const f32x4*)&wo[(long)i * 8 + 4];
    u32x4 o;
    o[0] = (u32)f2bf(a[0]) | ((u32)f2bf(a[1]) << 16);
    o[1] = (u32)f2bf(a[2]) | ((u32)f2bf(a[3]) << 16);
    o[2] = (u32)f2bf(b[0]) | ((u32)f2bf(b[1]) << 16);
    o[3] = (u32)f2bf(b[2]) | ((u32)f2bf(b[3]) << 16);
    *(u32x4*)&wo_bf[(long)i * 8] = o;
    return;
  }
  gid -= 131072;
  if (gid < 524288) {  // wp linear
    int i = (int)gid;
    f32x4 a = *(const f32x4*)&wp[(long)i * 8];
    f32x4 b = *(const f32x4*)&wp[(long)i * 8 + 4];
    u32x4 o;
    o[0] = (u32)f2bf(a[0]) | ((u32)f2bf(a[1]) << 16);
    o[1] = (u32)f2bf(a[2]) | ((u32)f2bf(a[3]) << 16);
    o[2] = (u32)f2bf(b[0]) | ((u32)f2bf(b[1]) << 16);
    o[3] = (u32)f2bf(b[2]) | ((u32)f2bf(b[3]) << 16);
    *(u32x4*)&wp_bf[(long)i * 8] = o;
    return;
  }
  gid -= 524288;
  {  // bias packs
    int i = (int)gid;
    if (i < 3 * DIM) {
      float v = (i < DIM) ? bq[i] : (i < 2 * DIM) ? bk[i - DIM] : bv[i - 2 * DIM];
      bqkv[i] = v;
    } else if (i < 3 * DIM + FF) {
      int j = i - 3 * DIM;
      bgv[2 * j] = bg[j];
      bgv[2 * j + 1] = bval[j];
    }
  }
}

// ---------------- RMSNorm: fp32 row -> bf16 row, K-unit XOR-preswizzled out ----------------
__global__ __launch_bounds__(256) void rmsnorm_kernel(const float* __restrict__ x,
                                                      const float* __restrict__ w,
                                                      u16* __restrict__ out) {
  const int row = blockIdx.x;
  const int tid = threadIdx.x;
  const long base = (long)row * DIM + tid * 4;
  f32x4 v = *(const f32x4*)&x[base];
  float ss = v[0] * v[0] + v[1] * v[1] + v[2] * v[2] + v[3] * v[3];
#pragma unroll
  for (int d = 1; d <= 32; d <<= 1) ss += __shfl_xor(ss, d, 64);
  __shared__ float red[4];
  if ((tid & 63) == 0) red[tid >> 6] = ss;
  __syncthreads();
  float tot = red[0] + red[1] + red[2] + red[3];
  const float sc = rsqrtf(tot * (1.f / (float)DIM) + 1e-6f);
  f32x4 wv4 = *(const f32x4*)&w[tid * 4];
  u32x2 o;
  o[0] = (u32)f2bf(v[0] * sc * wv4[0]) | ((u32)f2bf(v[1] * sc * wv4[1]) << 16);
  o[1] = (u32)f2bf(v[2] * sc * wv4[2]) | ((u32)f2bf(v[3] * sc * wv4[3]) << 16);
  const int u = tid >> 1, hf = tid & 1;
  const int up = (u & 0x78) | ((u & 7) ^ (row & 7));
  *(u32x2*)&out[(long)row * DIM + up * 8 + hf * 4] = o;
}

// ---------------- 256x256 GEMM, faithful m201 8-phase schedule ----------------
// Iteration = 2 K-tiles (even tile->buf0, odd->buf1). Quad order per tile:
// (0,0),(1,0),(0,1),(1,1). Each phase: {ds_read subtile; stage ONE half-slice;
// barrier; lgkmcnt(0); 16 MFMA; barrier}. Staged slice's region was last read
// one phase earlier (WAR-safe). vmcnt(4) at end-ph3/ph7 drains exactly the
// 4 slices of the next-needed K-tile, leaving 2 slices in flight.
template <int EPI>
__global__ __launch_bounds__(512, 2) void gemm256(const u16* __restrict__ A,
                                                  const u16* __restrict__ Bw,
                                                  const float* __restrict__ bias,
                                                  u16* __restrict__ out_bf,
                                                  int N, int K) {
  __shared__ __align__(16) u16 Ab[2][256 * 64];
  __shared__ __align__(16) u16 Bb[2][256 * 64];
  const int tid = threadIdx.x;
  const int lane = tid & 63;
  const int wid = tid >> 6;
  const int wm = wid >> 2, wn = wid & 3;
  const int l15 = lane & 15, lhi = lane >> 4;
  const int c7 = l15 & 7;
  const long m0 = (long)blockIdx.y * 256;
  const long n0 = (long)blockIdx.x * 256;
  const int NI = K >> 7;  // iterations of 2 K-tiles

  const int srowA = tid >> 3;            // 0..63
  const int sunit = (tid & 7) * 8;
  const u16* agp = A + (m0 + srowA) * K + sunit;
  const int aofs = srowA * 64 + (tid & 7) * 8;
  const int wgrp = tid >> 8;             // 0..1
  const int srow32 = (tid >> 3) & 31;    // 0..31
  const u16* bgp = Bw + (n0 + wgrp * 64 + srow32) * K + sunit;
  const int bofs = (wgrp * 64 + srow32) * 64 + (tid & 7) * 8;

  // stage A MH-slice of K-tile kt into buf b: rows {c*128 + MH*64 + srowA}
  auto stA = [&](int kt, int b, int MH) {
#pragma unroll
    for (int c = 0; c < 2; ++c)
      gl_lds16(agp + (long)(c * 128 + MH * 64) * K + (kt << 6),
               &Ab[b][(c * 128 + MH * 64) * 64 + aofs]);
  };
  // stage B NH-slice: rows {(c*2+wgrp)*64 + NH*32 + srow32}
  auto stB = [&](int kt, int b, int NHs) {
#pragma unroll
    for (int c = 0; c < 2; ++c)
      gl_lds16(bgp + (long)(c * 128 + NHs * 32) * K + (kt << 6),
               &Bb[b][(c * 128 + NHs * 32) * 64 + bofs]);
  };

#define READ_A(arr, MH, Ac)                                                      \
  _Pragma("unroll") for (int m_ = 0; m_ < 4; ++m_) {                             \
    _Pragma("unroll") for (int ks_ = 0; ks_ < 2; ++ks_) {                        \
      arr[m_ * 2 + ks_] =                                                        \
          *(const bf16x8*)&Ac[(wm * 128 + (MH)*64 + m_ * 16 + l15) * 64 +        \
                              (((ks_ * 4 + lhi) ^ c7) * 8)];                     \
    }                                                                            \
  }
#define READ_B(arr, NHs, Bc)                                                     \
  _Pragma("unroll") for (int n_ = 0; n_ < 2; ++n_) {                             \
    _Pragma("unroll") for (int ks_ = 0; ks_ < 2; ++ks_) {                        \
      arr[n_ * 2 + ks_] =                                                        \
          *(const bf16x8*)&Bc[(wn * 64 + (NHs)*32 + n_ * 16 + l15) * 64 +        \
                              (((ks_ * 4 + lhi) ^ c7) * 8)];                     \
    }                                                                            \
  }
#define QUADX(Aarr, Barr, MH, NHs)                                               \
  do {                                                                           \
    __builtin_amdgcn_s_setprio(1);                                               \
    _Pragma("unroll") for (int m_ = 0; m_ < 4; ++m_) {                           \
      _Pragma("unroll") for (int n_ = 0; n_ < 2; ++n_) {                         \
        acc[(MH)*4 + m_][(NHs)*2 + n_] =                                         \
            MFMA16(Aarr[m_ * 2], Barr[n_ * 2],                                   \
                   acc[(MH)*4 + m_][(NHs)*2 + n_], 0, 0, 0);                     \
        acc[(MH)*4 + m_][(NHs)*2 + n_] =                                         \
            MFMA16(Aarr[m_ * 2 + 1], Barr[n_ * 2 + 1],                           \
                   acc[(MH)*4 + m_][(NHs)*2 + n_], 0, 0, 0);                     \
      }                                                                          \
    }                                                                            \
    __builtin_amdgcn_s_setprio(0);                                               \
  } while (0)

  f32x4 acc[8][4] = {};

  // prologue: tile0 fully staged; tile1's B_NH0 + A_MH0 staged (stay in flight)
  stA(0, 0, 0);
  stB(0, 0, 0);
  stA(0, 0, 1);
  stB(0, 0, 1);
  stB(1, 1, 0);
  stA(1, 1, 0);
  asm volatile("s_waitcnt vmcnt(4)" ::: "memory");  // tile0 resident
  __builtin_amdgcn_s_barrier();
  GFENCE();

  for (int j = 0; j < NI; ++j) {
    const int ta = 2 * j, tb = 2 * j + 1;
    const bool sok = (j + 1 < NI);
    const u16* A0c = &Ab[0][0];
    const u16* B0c = &Bb[0][0];
    const u16* A1c = &Ab[1][0];
    const u16* B1c = &Bb[1][0];
    bf16x8 Af0[8], Af1[8], Bf0[4], Bf1[4];

    // ======== tile ta (buf0) ========
    // ph0: reads A_MH0+B_NH0; stage A_MH1(tb)->buf1 (last read prev ph7)
    READ_A(Af0, 0, A0c);
    READ_B(Bf0, 0, B0c);
    stA(tb, 1, 1);
    BARF();
    LGKM0();
    QUADX(Af0, Bf0, 0, 0);
    BARF();
    // ph1: reads A_MH1; stage B_NH1(tb)->buf1 (last read prev ph7)
    READ_A(Af1, 1, A0c);
    stB(tb, 1, 1);
    BARF();
    LGKM0();
    QUADX(Af1, Bf0, 1, 0);
    BARF();
    // ph2: reads B_NH1; stage B_NH0(ta+2)->buf0 (last read ph1)
    READ_B(Bf1, 1, B0c);
    if (sok) stB(ta + 2, 0, 0);
    BARF();
    LGKM0();
    QUADX(Af0, Bf1, 0, 1);
    BARF();
    // ph3: no reads; stage A_MH0(ta+2)->buf0 (last read ph2); boundary vmcnt
    if (sok) stA(ta + 2, 0, 0);
    BARF();
    QUADX(Af1, Bf1, 1, 1);
    if (sok)
      asm volatile("s_waitcnt vmcnt(4)" ::: "memory");  // tile tb resident
    else
      asm volatile("s_waitcnt vmcnt(0)" ::: "memory");
    __builtin_amdgcn_s_barrier();
    GFENCE();

    // ======== tile tb (buf1) ========
    // ph4: reads A_MH0+B_NH0 (buf1); stage A_MH1(ta+2)->buf0 (last read ph3)
    READ_A(Af0, 0, A1c);
    READ_B(Bf0, 0, B1c);
    if (sok) stA(ta + 2, 0, 1);
    BARF();
    LGKM0();
    QUADX(Af0, Bf0, 0, 0);
    BARF();
    // ph5: reads A_MH1; stage B_NH1(ta+2)->buf0 (last read ph3)
    READ_A(Af1, 1, A1c);
    if (sok) stB(ta + 2, 0, 1);
    BARF();
    LGKM0();
    QUADX(Af1, Bf0, 1, 0);
    BARF();
    // ph6: reads B_NH1; stage B_NH0(tb+2)->buf1 (last read ph5)
    READ_B(Bf1, 1, B1c);
    if (sok) stB(tb + 2, 1, 0);
    BARF();
    LGKM0();
    QUADX(Af0, Bf1, 0, 1);
    BARF();
    // ph7: no reads; stage A_MH0(tb+2)->buf1 (last read ph6); boundary vmcnt
    if (sok) stA(tb + 2, 1, 0);
    BARF();
    QUADX(Af1, Bf1, 1, 1);
    if (sok) {
      asm volatile("s_waitcnt vmcnt(4)" ::: "memory");  // tile ta+2 resident
      __builtin_amdgcn_s_barrier();
      GFENCE();
    }
  }
#undef READ_A
#undef READ_B
#undef QUADX

#pragma unroll
  for (int mi = 0; mi < 8; ++mi) {
    const long row0 = m0 + wm * 128 + mi * 16 + lhi * 4;
#pragma unroll
    for (int ni = 0; ni < 4; ++ni) {
      const long col = n0 + wn * 64 + ni * 16 + l15;
      const float bb = bias[col];
#pragma unroll
      for (int r = 0; r < 4; ++r) {
        float v = acc[mi][ni][r] + bb;
        if (EPI == 2) {
          float other = __shfl_xor(v, 1, 64);
          if (!(l15 & 1)) {
            float s = v / (1.f + __expf(-v)) * other;  // silu(g)*v
            out_bf[(row0 + r) * (N >> 1) + (col >> 1)] = f2bf(s);
          }
        } else {
          out_bf[(row0 + r) * N + col] = f2bf(v);
        }
      }
    }
  }
}

// ---------------- 3-buffer GEMM (linear layouts) for skinny N ----------------
template <int EPI, int NB>
__global__ __launch_bounds__(256) void gemm_bt(const u16* __restrict__ A,
                                               const u16* __restrict__ Bw,
                                               const float* __restrict__ bias,
                                               const float* __restrict__ resid,
                                               u16* __restrict__ out_bf,
                                               float* __restrict__ out_f,
                                               int N, int K) {
  constexpr int BHALF = NB / 64;
  constexpr int NFR = NB / 32;
  constexpr int LPT = 2 + BHALF;
  __shared__ __align__(16) u16 As[3][128 * 32];
  __shared__ __align__(16) u16 Bs[3][NB * 32];
  const int tid = threadIdx.x;
  const int lane = tid & 63;
  const int wv = tid >> 6;
  const int wr = wv >> 1, wc = wv & 1;
  const long m0 = (long)blockIdx.y * 128;
  const long n0 = (long)blockIdx.x * NB;

  const int arow = tid >> 2;
  const int acol = (tid & 3) << 3;
  const u16* ag = A + (m0 + arow) * K + acol;
  const u16* bg = Bw + (n0 + arow) * K + acol;
  const long hK = (long)64 * K;

  f32x4 acc[4][NFR] = {};
  const int l15 = lane & 15;
  const int lhi = lane >> 4;
  const int aoff0 = (wr * 64 + l15) * 32 + lhi * 8;
  const int boff0 = (wc * (NB / 2) + l15) * 32 + lhi * 8;
  const int nk = K >> 5;

  auto stage = [&](int t, int buf) {
    const int k0 = t << 5;
    gl_lds16(ag + k0, &As[buf][tid * 8]);
    gl_lds16(ag + k0 + hK, &As[buf][2048 + tid * 8]);
    gl_lds16(bg + k0, &Bs[buf][tid * 8]);
    if (BHALF == 2) gl_lds16(bg + k0 + hK, &Bs[buf][2048 + tid * 8]);
  };

  stage(0, 0);
  stage(1, 1);
  asm volatile("s_waitcnt vmcnt(%0)" ::"n"(LPT) : "memory");
  __builtin_amdgcn_s_barrier();
  GFENCE();

  for (int t = 0; t < nk; ++t) {
    const int cb = t % 3;
    if (t + 2 < nk) stage(t + 2, (t + 2) % 3);
    bf16x8 af[4], bfr[NFR];
#pragma unroll
    for (int i = 0; i < 4; ++i) af[i] = *(const bf16x8*)&As[cb][aoff0 + i * 16 * 32];
#pragma unroll
    for (int j = 0; j < NFR; ++j) bfr[j] = *(const bf16x8*)&Bs[cb][boff0 + j * 16 * 32];
    __builtin_amdgcn_s_setprio(1);
#pragma unroll
    for (int i = 0; i < 4; ++i)
#pragma unroll
      for (int j = 0; j < NFR; ++j)
        acc[i][j] = MFMA16(af[i], bfr[j], acc[i][j], 0, 0, 0);
    __builtin_amdgcn_s_setprio(0);
    if (t + 2 < nk) {
      asm volatile("s_waitcnt vmcnt(%0)" ::"n"(LPT) : "memory");
      __builtin_amdgcn_s_barrier();
      GFENCE();
    } else if (t + 1 < nk) {
      asm volatile("s_waitcnt vmcnt(0)" ::: "memory");
      __builtin_amdgcn_s_barrier();
      GFENCE();
    }
  }

#pragma unroll
  for (int i = 0; i < 4; ++i) {
    const long row0 = m0 + wr * 64 + i * 16 + lhi * 4;
#pragma unroll
    for (int j = 0; j < NFR; ++j) {
      const long col = n0 + wc * (NB / 2) + j * 16 + l15;
      const float bb = bias[col];
#pragma unroll
      for (int r = 0; r < 4; ++r) {
        const long idx = (row0 + r) * N + col;
        float v = acc[i][j][r] + bb;
        if (EPI == 0) out_bf[idx] = f2bf(v);
        else          out_f[idx] = resid[idx] + v;
      }
    }
  }
}

// ---------------- fused RoPE(Q), RoPE(K)+concat, V-transpose+concat ----------------
// blocks [0,2048): Q; [2048,5120): K; [5120,8192): Vt
__global__ __launch_bounds__(256) void rope_all_kernel(const u16* __restrict__ qkv,
                                                       const float* __restrict__ cache_k,
                                                       const float* __restrict__ cache_v,
                                                       const float* __restrict__ cosT,
                                                       const float* __restrict__ sinT,
                                                       u16* __restrict__ Q,
                                                       u16* __restrict__ Kall,
                                                       u16* __restrict__ Vtg) {
  const int blk = blockIdx.x;
  if (blk < 2048) {
    int idx = blk * 256 + threadIdx.x;  // B*H*S*8 = 524288 units of 8 elems
    int u = idx & 7;
    int s = (idx >> 3) & (S_LEN - 1);
    int bh = idx >> 14;
    int b = bh >> 4, h = bh & 15;
    int pos = PREV + s;
    const float SC = 0.125f * LOG2E;
    const u16* src = qkv + ((long)(b * S_LEN + s)) * (3 * DIM) + h * HD + u * 8;
    u32x4 d = *(const u32x4*)src;
    f32x4 cv = *(const f32x4*)&cosT[(long)pos * 32 + u * 4];
    f32x4 sv = *(const f32x4*)&sinT[(long)pos * 32 + u * 4];
    u32x4 o;
#pragma unroll
    for (int p = 0; p < 4; ++p) {
      float x0 = bf2f((u16)(d[p] & 0xffff));
      float x1 = bf2f((u16)(d[p] >> 16));
      float y0 = (x0 * cv[p] - x1 * sv[p]) * SC;
      float y1 = (x0 * sv[p] + x1 * cv[p]) * SC;
      o[p] = (u32)f2bf(y0) | ((u32)f2bf(y1) << 16);
    }
    *(u32x4*)&Q[((long)bh * S_LEN + s) * HD + u * 8] = o;
  } else if (blk < 5120) {
    int idx = (blk - 2048) * 256 + threadIdx.x;  // B*H*T*8 = 786432
    int u = idx & 7;
    int t2 = idx >> 3;
    int j = t2 % T_LEN;
    int bh = t2 / T_LEN;
    int b = bh >> 4, h = bh & 15;
    float e[8];
    if (j < PREV) {
      const float* src = cache_k + ((long)bh * PREV + j) * HD + u * 8;
      f32x4 a = *(const f32x4*)src;
      f32x4 c = *(const f32x4*)(src + 4);
      e[0] = a[0]; e[1] = a[1]; e[2] = a[2]; e[3] = a[3];
      e[4] = c[0]; e[5] = c[1]; e[6] = c[2]; e[7] = c[3];
    } else {
      const u16* src = qkv + ((long)(b * S_LEN + (j - PREV))) * (3 * DIM) + DIM + h * HD + u * 8;
      u32x4 d = *(const u32x4*)src;
#pragma unroll
      for (int p = 0; p < 4; ++p) {
        e[2 * p] = bf2f((u16)(d[p] & 0xffff));
        e[2 * p + 1] = bf2f((u16)(d[p] >> 16));
      }
    }
    f32x4 cv = *(const f32x4*)&cosT[(long)j * 32 + u * 4];
    f32x4 sv = *(const f32x4*)&sinT[(long)j * 32 + u * 4];
    u32x4 o;
#pragma unroll
    for (int p = 0; p < 4; ++p) {
      float y0 = e[2 * p] * cv[p] - e[2 * p + 1] * sv[p];
      float y1 = e[2 * p] * sv[p] + e[2 * p + 1] * cv[p];
      o[p] = (u32)f2bf(y0) | ((u32)f2bf(y1) << 16);
    }
    *(u32x4*)&Kall[((long)bh * T_LEN + j) * HD + (u ^ (j & 7)) * 8] = o;
  } else {
    int idx = (blk - 5120) * 256 + threadIdx.x;  // 32 * 384 * 64 = 786432
    int hd = idx & 63;
    int t2 = idx >> 6;
    int kb = t2 % 384;  // 8-key block
    int bh = t2 / 384;
    int b = bh >> 4, h = bh & 15;
    int key0 = kb * 8;
    u16 vals[8];
    if (key0 < PREV) {
#pragma unroll
      for (int i = 0; i < 8; ++i)
        vals[i] = f2bf(cache_v[((long)bh * PREV + key0 + i) * HD + hd]);
    } else {
#pragma unroll
      for (int i = 0; i < 8; ++i)
        vals[i] = qkv[((long)(b * S_LEN + key0 + i - PREV)) * (3 * DIM) + 2 * DIM + h * HD + hd];
    }
    u32x4 o;
#pragma unroll
    for (int p = 0; p < 4; ++p)
      o[p] = (u32)vals[2 * p] | ((u32)vals[2 * p + 1] << 16);
    const int span = kb >> 3;
    const int u = (kb & 7) ^ (hd & 7);
    *(u32x4*)&Vtg[((long)bh * HD + hd) * T_LEN + span * 64 + u * 8] = o;
  }
}

// ---------------- flash attention: paired dual-Q blocks, shared KV sweep ----------------
__global__ __launch_bounds__(256, 2) void attn_kernel(const u16* __restrict__ Q,
                                                      const u16* __restrict__ Kg,
                                                      const u16* __restrict__ Vtg,
                                                      u16* __restrict__ ctx, float slope2) {
  __shared__ __align__(16) u16 Ks[2][64 * 64];     // [key][d], swizzled
  __shared__ __align__(16) u16 Vs[2][64 * 64];     // [hd][key], swizzled
  __shared__ __align__(16) u16 Ps[2][4][16 * 64];  // per-qset per-wave P, swizzled

  const int tid = threadIdx.x;
  const int lane = tid & 63;
  const int wv = tid >> 6;
  const int l15 = lane & 15;
  const int lhi = lane >> 4;
  const int c7 = l15 & 7;
  const int bh = blockIdx.x;
  const int p = blockIdx.y;            // pair index 0..15
  const int b = bh >> 4, h = bh & 15;
  const int qA0 = p * 64;
  const int qB0 = (31 - p) * 64;
  const int ntA = 17 + p;              // (PREV + qA0 + 64) >> 6
  const int ntB = 48 - p;              // ntA + ntB = 65

  const long qrowA = (long)bh * S_LEN + qA0 + wv * 16 + l15;
  const long qrowB = (long)bh * S_LEN + qB0 + wv * 16 + l15;
  bf16x8 aqA0 = *(const bf16x8*)&Q[qrowA * HD + lhi * 8];
  bf16x8 aqA1 = *(const bf16x8*)&Q[qrowA * HD + 32 + lhi * 8];
  bf16x8 aqB0 = *(const bf16x8*)&Q[qrowB * HD + lhi * 8];
  bf16x8 aqB1 = *(const bf16x8*)&Q[qrowB * HD + 32 + lhi * 8];

  const long kgb = (long)bh * T_LEN * HD;  // K: [key][64]
  const long vgb = (long)bh * HD * T_LEN;  // Vt: [hd][T]
  const int srow = tid >> 3;               // staging row 0..31
  const int sunit = (tid & 7) * 8;

  const u16* kst = Kg + kgb + (long)srow * HD + sunit;     // +64*HD per tile
  const u16* vst = Vtg + vgb + (long)srow * T_LEN + sunit; // +64 per tile

  // prologue: stage tile 0
  gl_lds16(kst, &Ks[0][tid * 8]);
  gl_lds16(kst + 32 * HD, &Ks[0][2048 + tid * 8]);
  gl_lds16(vst, &Vs[0][tid * 8]);
  gl_lds16(vst + (long)32 * T_LEN, &Vs[0][2048 + tid * 8]);
  kst += 64 * HD;
  vst += 64;
  __syncthreads();

  f32x4 oA[4] = {}, oB[4] = {};
  f32x4 lrunA = {0.f, 0.f, 0.f, 0.f}, lrunB = {0.f, 0.f, 0.f, 0.f};
  float mrunA = -1e30f, mrunB = -1e30f;
  const int qq = wv * 16 + l15;  // local q (mask threshold, same layout both q-sets)

  f32x4 be[4];  // per-thread bias constants slope*(jf*16+4*lhi+r)
#pragma unroll
  for (int jf = 0; jf < 4; ++jf)
#pragma unroll
    for (int r = 0; r < 4; ++r)
      be[jf][r] = slope2 * (float)(jf * 16 + 4 * lhi + r);
  const float bmax = slope2 * 63.f;

  bf16x8 vones;
#pragma unroll
  for (int e = 0; e < 8; ++e) vones[e] = (__bf16)1.0f;

  float ktf = 0.f;
  const float kstep = slope2 * 64.f;

  // softmax + PV for one q-set (separate P buffer per q-set)
  auto process = [&](f32x4 (&sf)[4], bool maskNow, f32x4 (&o)[4], f32x4& lrun,
                     float& mrun, bf16x8 (&vf)[8], u16* Pw) {
    if (maskNow) {
#pragma unroll
      for (int jf = 0; jf < 4; ++jf)
#pragma unroll
        for (int r = 0; r < 4; ++r)
          if (jf * 16 + 4 * lhi + r > qq) sf[jf][r] = -1e30f;
    }
    float h0 = fmaxf(fmaxf(sf[0][0], sf[0][1]), fmaxf(sf[0][2], sf[0][3]));
    float h1 = fmaxf(fmaxf(sf[1][0], sf[1][1]), fmaxf(sf[1][2], sf[1][3]));
    float h2 = fmaxf(fmaxf(sf[2][0], sf[2][1]), fmaxf(sf[2][2], sf[2][3]));
    float h3 = fmaxf(fmaxf(sf[3][0], sf[3][1]), fmaxf(sf[3][2], sf[3][3]));
    float pm = fmaxf(fmaxf(h0, h1), fmaxf(h2, h3));
    pm = fmaxf(pm, __shfl_xor(pm, 16, 64));
    pm = fmaxf(pm, __shfl_xor(pm, 32, 64));
    const float pmax_abs = pm + ktf + bmax;

    if (!__all(pmax_abs - mrun <= 8.f)) {
      const float mnew = fmaxf(mrun, pmax_abs);
      const float scl = exp2f(mrun - mnew);
      mrun = mnew;
#pragma unroll
      for (int r = 0; r < 4; ++r) {
        const float sr = __shfl(scl, 4 * lhi + r, 64);
        lrun[r] *= sr;
#pragma unroll
        for (int hf = 0; hf < 4; ++hf) o[hf][r] *= sr;
      }
    }
    const float meff = mrun - ktf;

#pragma unroll
    for (int jf = 0; jf < 4; ++jf) {
      f32x4 pp;
#pragma unroll
      for (int r = 0; r < 4; ++r)
        pp[r] = exp2f(sf[jf][r] + (be[jf][r] - meff));
      u32x2 pw2;
      pw2[0] = cvtpk(pp[0], pp[1]);
      pw2[1] = cvtpk(pp[2], pp[3]);
      const int u = (2 * jf + (lhi >> 1)) ^ c7;
      *(u32x2*)&Pw[l15 * 64 + u * 8 + (lhi & 1) * 4] = pw2;
    }

    bf16x8 pa0 = *(const bf16x8*)&Pw[l15 * 64 + ((lhi ^ c7) * 8)];
    bf16x8 pa1 = *(const bf16x8*)&Pw[l15 * 64 + (((4 + lhi) ^ c7) * 8)];
    f32x4 psum = {};
    __builtin_amdgcn_s_setprio(1);
    psum = MFMA16(pa0, vones, psum, 0, 0, 0);
    psum = MFMA16(pa1, vones, psum, 0, 0, 0);
#pragma unroll
    for (int hf = 0; hf < 4; ++hf) {
      o[hf] = MFMA16(pa0, vf[2 * hf], o[hf], 0, 0, 0);
      o[hf] = MFMA16(pa1, vf[2 * hf + 1], o[hf], 0, 0, 0);
    }
    __builtin_amdgcn_s_setprio(0);
    lrun += psum;
  };

  for (int t = 0; t < ntB; ++t) {
    const int cur = t & 1, nxt = cur ^ 1;
    const bool lastStage = (t + 1 == ntB);
    if (!lastStage) {
      gl_lds16(kst, &Ks[nxt][tid * 8]);
      gl_lds16(kst + 32 * HD, &Ks[nxt][2048 + tid * 8]);
      gl_lds16(vst, &Vs[nxt][tid * 8]);
      gl_lds16(vst + (long)32 * T_LEN, &Vs[nxt][2048 + tid * 8]);
      kst += 64 * HD;
      vst += 64;
    }
    const bool actA = (t < ntA);

    // K fragments once, shared by both q-sets
    bf16x8 kf[8];
#pragma unroll
    for (int jf = 0; jf < 4; ++jf) {
      const int krow = jf * 16 + l15;
      kf[2 * jf] = *(const bf16x8*)&Ks[cur][krow * 64 + ((lhi ^ c7) * 8)];
      kf[2 * jf + 1] = *(const bf16x8*)&Ks[cur][krow * 64 + (((4 + lhi) ^ c7) * 8)];
    }
    // V fragments once, shared by both q-sets
    bf16x8 vf[8];
#pragma unroll
    for (int hf = 0; hf < 4; ++hf) {
      const int vrow = hf * 16 + l15;
      vf[2 * hf] = *(const bf16x8*)&Vs[cur][vrow * 64 + ((lhi ^ c7) * 8)];
      vf[2 * hf + 1] = *(const bf16x8*)&Vs[cur][vrow * 64 + (((4 + lhi) ^ c7) * 8)];
    }

    // QK^T for both q-sets
    f32x4 sB[4], sA[4];
    __builtin_amdgcn_s_setprio(1);
#pragma unroll
    for (int jf = 0; jf < 4; ++jf) {
      f32x4 s = {};
      s = MFMA16(kf[2 * jf], aqB0, s, 0, 0, 0);
      s = MFMA16(kf[2 * jf + 1], aqB1, s, 0, 0, 0);
      sB[jf] = s;
    }
    __builtin_amdgcn_s_setprio(0);
    if (actA) {
      __builtin_amdgcn_s_setprio(1);
#pragma unroll
      for (int jf = 0; jf < 4; ++jf) {
        f32x4 s = {};
        s = MFMA16(kf[2 * jf], aqA0, s, 0, 0, 0);
        s = MFMA16(kf[2 * jf + 1], aqA1, s, 0, 0, 0);
        sA[jf] = s;
      }
      __builtin_amdgcn_s_setprio(0);
    }

    process(sB, t == ntB - 1, oB, lrunB, mrunB, vf, &Ps[0][wv][0]);
    if (actA) process(sA, t == ntA - 1, oA, lrunA, mrunA, vf, &Ps[1][wv][0]);

    ktf += kstep;
    if (!lastStage) __syncthreads();
  }

  // epilogue: rows q_local = 4*lhi + r; cols hd = hf*16 + l15
#pragma unroll
  for (int r = 0; r < 4; ++r) {
    const float invA = 1.f / lrunA[r];
    const float invB = 1.f / lrunB[r];
    const long rowA = (long)b * S_LEN + qA0 + wv * 16 + 4 * lhi + r;
    const long rowB = (long)b * S_LEN + qB0 + wv * 16 + 4 * lhi + r;
#pragma unroll
    for (int hf = 0; hf < 4; ++hf) {
      ctx[rowA * DIM + h * HD + hf * 16 + l15] = f2bf(oA[hf][r] * invA);
      ctx[rowB * DIM + h * HD + hf * 16 + l15] = f2bf(oB[hf][r] * invB);
    }
  }
}

// ---------------------------------------------------------------------------
extern "C" void kernel_launch(void* const* d_in, const int* in_sizes, int n_in,
                              void* d_out, int out_size, void* d_ws, size_t ws_size,
                              hipStream_t stream) {
  (void)in_sizes; (void)n_in; (void)out_size; (void)ws_size;
  const float* x       = (const float*)d_in[0];
  const float* cache_k = (const float*)d_in[1];
  const float* cache_v = (const float*)d_in[2];
  const float* cosT    = (const float*)d_in[3];
  const float* sinT    = (const float*)d_in[4];
  const float* attn_w  = (const float*)d_in[5];
  const float* ffn_w   = (const float*)d_in[6];
  const float* wq      = (const float*)d_in[7];
  const float* bq      = (const float*)d_in[8];
  const float* wk      = (const float*)d_in[9];
  const float* bk      = (const float*)d_in[10];
  const float* wv_     = (const float*)d_in[11];
  const float* bv      = (const float*)d_in[12];
  const float* wo      = (const float*)d_in[13];
  const float* bo      = (const float*)d_in[14];
  const float* wg      = (const float*)d_in[15];
  const float* bg      = (const float*)d_in[16];
  const float* wval    = (const float*)d_in[17];
  const float* bval    = (const float*)d_in[18];
  const float* wp      = (const float*)d_in[19];
  const float* bp      = (const float*)d_in[20];
  float* out = (float*)d_out;

  char* w = (char*)d_ws;
  size_t off = 0;
  auto alloc = [&](size_t bytes) -> char* {
    char* p = w + off;
    off += (bytes + 255) & ~(size_t)255;
    return p;
  };
  // permanent
  u16*   wqkv_bf  = (u16*)alloc((size_t)3 * DIM * DIM * 2);  // preswizzled
  u16*   wo_bf    = (u16*)alloc((size_t)DIM * DIM * 2);      // linear
  u16*   wgv_bf   = (u16*)alloc((size_t)2 * FF * DIM * 2);   // interleaved+preswizzled
  u16*   wproj_bf = (u16*)alloc((size_t)DIM * FF * 2);       // linear
  float* bqkv     = (float*)alloc((size_t)3 * DIM * 4);
  float* bgv      = (float*)alloc((size_t)2 * FF * 4);       // interleaved
  float* x2       = (float*)alloc((size_t)MROWS * DIM * 4);
  // arena with lifetime-based aliasing
  char* AR = alloc((size_t)117440512);
  u16* qkv   = (u16*)(AR + 0);          // [4096][3072]   live: qkv gemm -> rope/build
  u16* Qb    = (u16*)(AR + 25165824);   // [32][2048][64] live: rope -> attn
  u16* Kb    = (u16*)(AR + 33554432);   // [32][3072][64]
  u16* Vtg   = (u16*)(AR + 46137344);   // [32][64][3072] transposed V
  u16* h1    = (u16*)(AR + 58720256);   // [4096][1024]   preswizzled (qkv gemm A)
  u16* ctx   = (u16*)(AR + 0);          // [4096][1024]   linear (aliases dead qkv)
  u16* h2    = (u16*)(AR + 8388608);    // [4096][1024]   preswizzled (gv gemm A)
  u16* gated = (u16*)(AR + 16777216);   // [4096][4096]   linear

  // 1) ALL weight + bias conversion in one launch
  cvt_all_kernel<<<6172, 256, 0, stream>>>(wq, wk, wv_, wg, wval, wo, wp,
                                           bq, bk, bv, bg, bval,
                                           wqkv_bf, wgv_bf, wo_bf, wproj_bf,
                                           bqkv, bgv);

  // 2) attn rmsnorm (swizzled out), fused QKV 256-gemm
  rmsnorm_kernel<<<MROWS, 256, 0, stream>>>(x, attn_w, h1);
  gemm256<0><<<dim3(12, 16), 512, 0, stream>>>(h1, wqkv_bf, bqkv, qkv, 3 * DIM, DIM);
  // 3) fused rope + cache concat (1 launch)
  rope_all_kernel<<<8192, 256, 0, stream>>>(qkv, cache_k, cache_v, cosT, sinT,
                                            Qb, Kb, Vtg);
  // 4) attention: paired dual-Q blocks
  attn_kernel<<<dim3(B_SZ * NH, 16), 256, 0, stream>>>(
      Qb, Kb, Vtg, ctx, (2.0f / (float)(T_LEN - 1)) * LOG2E);
  // 5) o-proj + residual (fp32), skinny tile
  gemm_bt<1, 64><<<dim3(16, 32), 256, 0, stream>>>(ctx, wo_bf, bo, x, nullptr, x2,
                                                   DIM, DIM);
  // 6) ffn rmsnorm (swizzled out), gate+value 256-gemm w/ silu epilogue, proj + residual
  rmsnorm_kernel<<<MROWS, 256, 0, stream>>>(x2, ffn_w, h2);
  gemm256<2><<<dim3(32, 16), 512, 0, stream>>>(h2, wgv_bf, bgv, gated, 2 * FF, DIM);
  gemm_bt<1, 64><<<dim3(16, 32), 256, 0, stream>>>(gated, wproj_bf, bp, x2, nullptr, out,
                                                   DIM, FF);
}

// Round 12
// 349.719 us; speedup vs baseline: 1.0096x; 1.0071x over previous
//
#include <hip/hip_runtime.h>
#include <stdint.h>

typedef unsigned short u16;
typedef unsigned int   u32;
typedef __bf16 bf16x8 __attribute__((ext_vector_type(8)));
typedef float  f32x4  __attribute__((ext_vector_type(4)));
typedef u32    u32x4  __attribute__((ext_vector_type(4)));
typedef u32    u32x2  __attribute__((ext_vector_type(2)));

#define B_SZ  2
#define S_LEN 2048
#define NH    16
#define HD    64
#define DIM   1024
#define FF    4096
#define T_LEN 3072
#define PREV  1024
#define MROWS (B_SZ * S_LEN) /* 4096 */
#define LOG2E 1.44269504f

#define MFMA16 __builtin_amdgcn_mfma_f32_16x16x32_bf16

__device__ __forceinline__ u16 f2bf(float f) {
  u32 u = __builtin_bit_cast(u32, f);
  u32 r = u + 0x7FFFu + ((u >> 16) & 1u);
  return (u16)(r >> 16);
}
__device__ __forceinline__ float bf2f(u16 h) {
  u32 u = ((u32)h) << 16;
  return __builtin_bit_cast(float, u);
}
__device__ __forceinline__ u32 cvtpk(float lo, float hi) {
  u32 r;
  asm("v_cvt_pk_bf16_f32 %0, %1, %2" : "=v"(r) : "v"(lo), "v"(hi));
  return r;
}

// async global->LDS, 16B per lane. LDS dest must be wave-uniform base + lane*16.
__device__ __forceinline__ void gl_lds16(const void* g, void* l) {
  __builtin_amdgcn_global_load_lds(
      (const __attribute__((address_space(1))) u32*)g,
      (__attribute__((address_space(3))) u32*)l, 16, 0, 0);
}

#define GFENCE() asm volatile("" ::: "memory")
#define BARF()                         \
  do {                                 \
    GFENCE();                          \
    __builtin_amdgcn_s_barrier();      \
    GFENCE();                          \
  } while (0)

// ---------------- ALL weight/bias conversion in ONE launch ----------------
__global__ __launch_bounds__(256) void cvt_all_kernel(
    const float* __restrict__ wq, const float* __restrict__ wk,
    const float* __restrict__ wv, const float* __restrict__ wg,
    const float* __restrict__ wval, const float* __restrict__ wo,
    const float* __restrict__ wp, const float* __restrict__ bq,
    const float* __restrict__ bk, const float* __restrict__ bv,
    const float* __restrict__ bg, const float* __restrict__ bval,
    u16* __restrict__ wqkv_bf, u16* __restrict__ wgv_bf,
    u16* __restrict__ wo_bf, u16* __restrict__ wp_bf,
    float* __restrict__ bqkv, float* __restrict__ bgv) {
  long gid = (long)blockIdx.x * 256 + threadIdx.x;
  if (gid < 393216) {  // wqkv, K-unit XOR-preswizzled
    int i = (int)gid;
    const int seg = i >> 17;
    const int loc = i & 131071;
    const float* src = (seg == 0) ? wq : (seg == 1) ? wk : wv;
    int row = loc >> 7;
    int g = loc & 127;
    const float* s = &src[((long)row << 10) + g * 8];
    f32x4 a = *(const f32x4*)s;
    f32x4 b = *(const f32x4*)(s + 4);
    u32x4 o;
    o[0] = (u32)f2bf(a[0]) | ((u32)f2bf(a[1]) << 16);
    o[1] = (u32)f2bf(a[2]) | ((u32)f2bf(a[3]) << 16);
    o[2] = (u32)f2bf(b[0]) | ((u32)f2bf(b[1]) << 16);
    o[3] = (u32)f2bf(b[2]) | ((u32)f2bf(b[3]) << 16);
    const int gp = (g & ~7) | ((g & 7) ^ (row & 7));
    *(u32x4*)&wqkv_bf[((long)seg << 20) + ((long)row << 10) + gp * 8] = o;
    return;
  }
  gid -= 393216;
  if (gid < 524288) {  // wgv interleave + preswizzle
    int i = (int)gid;
    int j = i >> 7;
    int g = i & 127;
    const float* sg = &wg[((long)j << 10) + g * 8];
    const float* sv = &wval[((long)j << 10) + g * 8];
    f32x4 a = *(const f32x4*)sg;
    f32x4 b = *(const f32x4*)(sg + 4);
    u32x4 og;
    og[0] = (u32)f2bf(a[0]) | ((u32)f2bf(a[1]) << 16);
    og[1] = (u32)f2bf(a[2]) | ((u32)f2bf(a[3]) << 16);
    og[2] = (u32)f2bf(b[0]) | ((u32)f2bf(b[1]) << 16);
    og[3] = (u32)f2bf(b[2]) | ((u32)f2bf(b[3]) << 16);
    f32x4 c = *(const f32x4*)sv;
    f32x4 d = *(const f32x4*)(sv + 4);
    u32x4 ov;
    ov[0] = (u32)f2bf(c[0]) | ((u32)f2bf(c[1]) << 16);
    ov[1] = (u32)f2bf(c[2]) | ((u32)f2bf(c[3]) << 16);
    ov[2] = (u32)f2bf(d[0]) | ((u32)f2bf(d[1]) << 16);
    ov[3] = (u32)f2bf(d[2]) | ((u32)f2bf(d[3]) << 16);
    const int rg = 2 * j, rv = 2 * j + 1;
    const int gpg = (g & ~7) | ((g & 7) ^ (rg & 7));
    const int gpv = (g & ~7) | ((g & 7) ^ (rv & 7));
    *(u32x4*)&wgv_bf[((long)rg << 10) + gpg * 8] = og;
    *(u32x4*)&wgv_bf[((long)rv << 10) + gpv * 8] = ov;
    return;
  }
  gid -= 524288;
  if (gid < 131072) {  // wo linear
    int i = (int)gid;
    f32x4 a = *(const f32x4*)&wo[(long)i * 8];
    f32x4 b = *(const f32x4*)&wo[(long)i * 8 + 4];
    u32x4 o;
    o[0] = (u32)f2bf(a[0]) | ((u32)f2bf(a[1]) << 16);
    o[1] = (u32)f2bf(a[2]) | ((u32)f2bf(a[3]) << 16);
    o[2] = (u32)f2bf(b[0]) | ((u32)f2bf(b[1]) << 16);
    o[3] = (u32)f2bf(b[2]) | ((u32)f2bf(b[3]) << 16);
    *(u32x4*)&wo_bf[(long)i * 8] = o;
    return;
  }
  gid -= 131072;
  if (gid < 524288) {  // wp linear
    int i = (int)gid;
    f32x4 a = *(const f32x4*)&wp[(long)i * 8];
    f32x4 b = *(const f32x4*)&wp[(long)i * 8 + 4];
    u32x4 o;
    o[0] = (u32)f2bf(a[0]) | ((u32)f2bf(a[1]) << 16);
    o[1] = (u32)f2bf(a[2]) | ((u32)f2bf(a[3]) << 16);
    o[2] = (u32)f2bf(b[0]) | ((u32)f2bf(b[1]) << 16);
    o[3] = (u32)f2bf(b[2]) | ((u32)f2bf(b[3]) << 16);
    *(u32x4*)&wp_bf[(long)i * 8] = o;
    return;
  }
  gid -= 524288;
  {  // bias packs
    int i = (int)gid;
    if (i < 3 * DIM) {
      float v = (i < DIM) ? bq[i] : (i < 2 * DIM) ? bk[i - DIM] : bv[i - 2 * DIM];
      bqkv[i] = v;
    } else if (i < 3 * DIM + FF) {
      int j = i - 3 * DIM;
      bgv[2 * j] = bg[j];
      bgv[2 * j + 1] = bval[j];
    }
  }
}

// ---------------- RMSNorm: fp32 row -> bf16 row, K-unit XOR-preswizzled out ----------------
__global__ __launch_bounds__(256) void rmsnorm_kernel(const float* __restrict__ x,
                                                      const float* __restrict__ w,
                                                      u16* __restrict__ out) {
  const int row = blockIdx.x;
  const int tid = threadIdx.x;
  const long base = (long)row * DIM + tid * 4;
  f32x4 v = *(const f32x4*)&x[base];
  float ss = v[0] * v[0] + v[1] * v[1] + v[2] * v[2] + v[3] * v[3];
#pragma unroll
  for (int d = 1; d <= 32; d <<= 1) ss += __shfl_xor(ss, d, 64);
  __shared__ float red[4];
  if ((tid & 63) == 0) red[tid >> 6] = ss;
  __syncthreads();
  float tot = red[0] + red[1] + red[2] + red[3];
  const float sc = rsqrtf(tot * (1.f / (float)DIM) + 1e-6f);
  f32x4 wv4 = *(const f32x4*)&w[tid * 4];
  u32x2 o;
  o[0] = (u32)f2bf(v[0] * sc * wv4[0]) | ((u32)f2bf(v[1] * sc * wv4[1]) << 16);
  o[1] = (u32)f2bf(v[2] * sc * wv4[2]) | ((u32)f2bf(v[3] * sc * wv4[3]) << 16);
  const int u = tid >> 1, hf = tid & 1;
  const int up = (u & 0x78) | ((u & 7) ^ (row & 7));
  *(u32x2*)&out[(long)row * DIM + up * 8 + hf * 4] = o;
}

// ---------------- 256x256 GEMM, 2-barrier K-tile (r9 best), K multiple of 64 ----------
// Per tile: read all 24 frags; Q00+Q10 (B0 dies) overlap reads; lgkm-drain+barrier
// (all waves' reads sampled -> buf overwrite-safe); stage kt+2; Q01+Q11; vmcnt(8)+barrier.
template <int EPI>
__global__ __launch_bounds__(512, 2) void gemm256(const u16* __restrict__ A,
                                                  const u16* __restrict__ Bw,
                                                  const float* __restrict__ bias,
                                                  u16* __restrict__ out_bf,
                                                  int N, int K) {
  __shared__ __align__(16) u16 Ab[2][256 * 64];
  __shared__ __align__(16) u16 Bb[2][256 * 64];
  const int tid = threadIdx.x;
  const int lane = tid & 63;
  const int wid = tid >> 6;
  const int wm = wid >> 2, wn = wid & 3;
  const int l15 = lane & 15, lhi = lane >> 4;
  const int c7 = l15 & 7;
  const long m0 = (long)blockIdx.y * 256;
  const long n0 = (long)blockIdx.x * 256;
  const int NT = K >> 6;

  const int srow = tid >> 3;
  const int sunit = (tid & 7) * 8;
  const u16* agp = A + (m0 + srow) * K + sunit;
  const u16* bgp = Bw + (n0 + srow) * K + sunit;
  const int ldst = tid * 8;

  auto stageA = [&](int kt, int b) {
    const int k0 = kt << 6;
    u16* d = &Ab[b][0];
#pragma unroll
    for (int c = 0; c < 4; ++c)
      gl_lds16(agp + (long)(c * 64) * K + k0, d + c * 4096 + ldst);
  };
  auto stageB = [&](int kt, int b) {
    const int k0 = kt << 6;
    u16* d = &Bb[b][0];
#pragma unroll
    for (int c = 0; c < 4; ++c)
      gl_lds16(bgp + (long)(c * 64) * K + k0, d + c * 4096 + ldst);
  };

#define READ_A(MH)                                                               \
  _Pragma("unroll") for (int m_ = 0; m_ < 4; ++m_) {                             \
    _Pragma("unroll") for (int ks_ = 0; ks_ < 2; ++ks_) {                        \
      Afr[MH][m_ * 2 + ks_] =                                                    \
          *(const bf16x8*)&Ac[(wm * 128 + (MH)*64 + m_ * 16 + l15) * 64 +        \
                              (((ks_ * 4 + lhi) ^ c7) * 8)];                     \
    }                                                                            \
  }
#define READ_B(NH)                                                               \
  _Pragma("unroll") for (int n_ = 0; n_ < 2; ++n_) {                             \
    _Pragma("unroll") for (int ks_ = 0; ks_ < 2; ++ks_) {                        \
      Bfr[NH][n_ * 2 + ks_] =                                                    \
          *(const bf16x8*)&Bc[(wn * 64 + (NH)*32 + n_ * 16 + l15) * 64 +         \
                              (((ks_ * 4 + lhi) ^ c7) * 8)];                     \
    }                                                                            \
  }
#define QUAD(MH, NH)                                                             \
  do {                                                                           \
    __builtin_amdgcn_s_setprio(1);                                               \
    _Pragma("unroll") for (int m_ = 0; m_ < 4; ++m_) {                           \
      _Pragma("unroll") for (int n_ = 0; n_ < 2; ++n_) {                         \
        acc[(MH)*4 + m_][(NH)*2 + n_] =                                          \
            MFMA16(Afr[MH][m_ * 2], Bfr[NH][n_ * 2],                             \
                   acc[(MH)*4 + m_][(NH)*2 + n_], 0, 0, 0);                      \
        acc[(MH)*4 + m_][(NH)*2 + n_] =                                          \
            MFMA16(Afr[MH][m_ * 2 + 1], Bfr[NH][n_ * 2 + 1],                     \
                   acc[(MH)*4 + m_][(NH)*2 + n_], 0, 0, 0);                      \
      }                                                                          \
    }                                                                            \
    __builtin_amdgcn_s_setprio(0);                                               \
  } while (0)

  f32x4 acc[8][4] = {};

  // prologue: tiles 0,1 staged; wait tile 0 (tile 1 stays in flight)
  stageA(0, 0);
  stageB(0, 0);
  stageA(1, 1);
  stageB(1, 1);
  asm volatile("s_waitcnt vmcnt(8)" ::: "memory");
  __builtin_amdgcn_s_barrier();
  GFENCE();

  for (int kt = 0; kt < NT; ++kt) {
    const int b = kt & 1;
    const u16* Ac = &Ab[b][0];
    const u16* Bc = &Bb[b][0];
    bf16x8 Afr[2][8], Bfr[2][4];
    // read everything for this tile (24 ds_read_b128), overlap with first 32 MFMA
    READ_A(0);
    READ_B(0);
    READ_A(1);
    READ_B(1);
    QUAD(0, 0);
    QUAD(1, 0);  // B-half0 dead after this
    // all this tile's LDS reads sampled before anyone overwrites buf b
    asm volatile("s_waitcnt lgkmcnt(0)" ::: "memory");
    __builtin_amdgcn_sched_barrier(0);
    __builtin_amdgcn_s_barrier();
    GFENCE();
    if (kt + 2 < NT) {
      stageA(kt + 2, b);
      stageB(kt + 2, b);
    }
    QUAD(0, 1);
    QUAD(1, 1);
    // boundary: tile kt+1 must be resident; keep kt+2 prefetch in flight
    if (kt + 1 < NT) {
      if (kt + 2 < NT)
        asm volatile("s_waitcnt vmcnt(8)" ::: "memory");
      else
        asm volatile("s_waitcnt vmcnt(0)" ::: "memory");
      __builtin_amdgcn_s_barrier();
      GFENCE();
    }
  }
#undef READ_A
#undef READ_B
#undef QUAD

#pragma unroll
  for (int mi = 0; mi < 8; ++mi) {
    const long row0 = m0 + wm * 128 + mi * 16 + lhi * 4;
#pragma unroll
    for (int ni = 0; ni < 4; ++ni) {
      const long col = n0 + wn * 64 + ni * 16 + l15;
      const float bb = bias[col];
#pragma unroll
      for (int r = 0; r < 4; ++r) {
        float v = acc[mi][ni][r] + bb;
        if (EPI == 2) {
          float other = __shfl_xor(v, 1, 64);
          if (!(l15 & 1)) {
            float s = v / (1.f + __expf(-v)) * other;  // silu(g)*v
            out_bf[(row0 + r) * (N >> 1) + (col >> 1)] = f2bf(s);
          }
        } else {
          out_bf[(row0 + r) * N + col] = f2bf(v);
        }
      }
    }
  }
}

// ---------------- 3-buffer GEMM (linear layouts) for skinny N ----------------
template <int EPI, int NB>
__global__ __launch_bounds__(256) void gemm_bt(const u16* __restrict__ A,
                                               const u16* __restrict__ Bw,
                                               const float* __restrict__ bias,
                                               const float* __restrict__ resid,
                                               u16* __restrict__ out_bf,
                                               float* __restrict__ out_f,
                                               int N, int K) {
  constexpr int BHALF = NB / 64;
  constexpr int NFR = NB / 32;
  constexpr int LPT = 2 + BHALF;
  __shared__ __align__(16) u16 As[3][128 * 32];
  __shared__ __align__(16) u16 Bs[3][NB * 32];
  const int tid = threadIdx.x;
  const int lane = tid & 63;
  const int wv = tid >> 6;
  const int wr = wv >> 1, wc = wv & 1;
  const long m0 = (long)blockIdx.y * 128;
  const long n0 = (long)blockIdx.x * NB;

  const int arow = tid >> 2;
  const int acol = (tid & 3) << 3;
  const u16* ag = A + (m0 + arow) * K + acol;
  const u16* bg = Bw + (n0 + arow) * K + acol;
  const long hK = (long)64 * K;

  f32x4 acc[4][NFR] = {};
  const int l15 = lane & 15;
  const int lhi = lane >> 4;
  const int aoff0 = (wr * 64 + l15) * 32 + lhi * 8;
  const int boff0 = (wc * (NB / 2) + l15) * 32 + lhi * 8;
  const int nk = K >> 5;

  auto stage = [&](int t, int buf) {
    const int k0 = t << 5;
    gl_lds16(ag + k0, &As[buf][tid * 8]);
    gl_lds16(ag + k0 + hK, &As[buf][2048 + tid * 8]);
    gl_lds16(bg + k0, &Bs[buf][tid * 8]);
    if (BHALF == 2) gl_lds16(bg + k0 + hK, &Bs[buf][2048 + tid * 8]);
  };

  stage(0, 0);
  stage(1, 1);
  asm volatile("s_waitcnt vmcnt(%0)" ::"n"(LPT) : "memory");
  __builtin_amdgcn_s_barrier();
  GFENCE();

  for (int t = 0; t < nk; ++t) {
    const int cb = t % 3;
    if (t + 2 < nk) stage(t + 2, (t + 2) % 3);
    bf16x8 af[4], bfr[NFR];
#pragma unroll
    for (int i = 0; i < 4; ++i) af[i] = *(const bf16x8*)&As[cb][aoff0 + i * 16 * 32];
#pragma unroll
    for (int j = 0; j < NFR; ++j) bfr[j] = *(const bf16x8*)&Bs[cb][boff0 + j * 16 * 32];
    __builtin_amdgcn_s_setprio(1);
#pragma unroll
    for (int i = 0; i < 4; ++i)
#pragma unroll
      for (int j = 0; j < NFR; ++j)
        acc[i][j] = MFMA16(af[i], bfr[j], acc[i][j], 0, 0, 0);
    __builtin_amdgcn_s_setprio(0);
    if (t + 2 < nk) {
      asm volatile("s_waitcnt vmcnt(%0)" ::"n"(LPT) : "memory");
      __builtin_amdgcn_s_barrier();
      GFENCE();
    } else if (t + 1 < nk) {
      asm volatile("s_waitcnt vmcnt(0)" ::: "memory");
      __builtin_amdgcn_s_barrier();
      GFENCE();
    }
  }

#pragma unroll
  for (int i = 0; i < 4; ++i) {
    const long row0 = m0 + wr * 64 + i * 16 + lhi * 4;
#pragma unroll
    for (int j = 0; j < NFR; ++j) {
      const long col = n0 + wc * (NB / 2) + j * 16 + l15;
      const float bb = bias[col];
#pragma unroll
      for (int r = 0; r < 4; ++r) {
        const long idx = (row0 + r) * N + col;
        float v = acc[i][j][r] + bb;
        if (EPI == 0) out_bf[idx] = f2bf(v);
        else          out_f[idx] = resid[idx] + v;
      }
    }
  }
}

// ---------------- fused RoPE(Q), RoPE(K)+concat, V-transpose+concat ----------------
// blocks [0,2048): Q; [2048,5120): K; [5120,8192): Vt
__global__ __launch_bounds__(256) void rope_all_kernel(const u16* __restrict__ qkv,
                                                       const float* __restrict__ cache_k,
                                                       const float* __restrict__ cache_v,
                                                       const float* __restrict__ cosT,
                                                       const float* __restrict__ sinT,
                                                       u16* __restrict__ Q,
                                                       u16* __restrict__ Kall,
                                                       u16* __restrict__ Vtg) {
  const int blk = blockIdx.x;
  if (blk < 2048) {
    int idx = blk * 256 + threadIdx.x;  // B*H*S*8 = 524288 units of 8 elems
    int u = idx & 7;
    int s = (idx >> 3) & (S_LEN - 1);
    int bh = idx >> 14;
    int b = bh >> 4, h = bh & 15;
    int pos = PREV + s;
    const float SC = 0.125f * LOG2E;
    const u16* src = qkv + ((long)(b * S_LEN + s)) * (3 * DIM) + h * HD + u * 8;
    u32x4 d = *(const u32x4*)src;
    f32x4 cv = *(const f32x4*)&cosT[(long)pos * 32 + u * 4];
    f32x4 sv = *(const f32x4*)&sinT[(long)pos * 32 + u * 4];
    u32x4 o;
#pragma unroll
    for (int p = 0; p < 4; ++p) {
      float x0 = bf2f((u16)(d[p] & 0xffff));
      float x1 = bf2f((u16)(d[p] >> 16));
      float y0 = (x0 * cv[p] - x1 * sv[p]) * SC;
      float y1 = (x0 * sv[p] + x1 * cv[p]) * SC;
      o[p] = (u32)f2bf(y0) | ((u32)f2bf(y1) << 16);
    }
    *(u32x4*)&Q[((long)bh * S_LEN + s) * HD + u * 8] = o;
  } else if (blk < 5120) {
    int idx = (blk - 2048) * 256 + threadIdx.x;  // B*H*T*8 = 786432
    int u = idx & 7;
    int t2 = idx >> 3;
    int j = t2 % T_LEN;
    int bh = t2 / T_LEN;
    int b = bh >> 4, h = bh & 15;
    float e[8];
    if (j < PREV) {
      const float* src = cache_k + ((long)bh * PREV + j) * HD + u * 8;
      f32x4 a = *(const f32x4*)src;
      f32x4 c = *(const f32x4*)(src + 4);
      e[0] = a[0]; e[1] = a[1]; e[2] = a[2]; e[3] = a[3];
      e[4] = c[0]; e[5] = c[1]; e[6] = c[2]; e[7] = c[3];
    } else {
      const u16* src = qkv + ((long)(b * S_LEN + (j - PREV))) * (3 * DIM) + DIM + h * HD + u * 8;
      u32x4 d = *(const u32x4*)src;
#pragma unroll
      for (int p = 0; p < 4; ++p) {
        e[2 * p] = bf2f((u16)(d[p] & 0xffff));
        e[2 * p + 1] = bf2f((u16)(d[p] >> 16));
      }
    }
    f32x4 cv = *(const f32x4*)&cosT[(long)j * 32 + u * 4];
    f32x4 sv = *(const f32x4*)&sinT[(long)j * 32 + u * 4];
    u32x4 o;
#pragma unroll
    for (int p = 0; p < 4; ++p) {
      float y0 = e[2 * p] * cv[p] - e[2 * p + 1] * sv[p];
      float y1 = e[2 * p] * sv[p] + e[2 * p + 1] * cv[p];
      o[p] = (u32)f2bf(y0) | ((u32)f2bf(y1) << 16);
    }
    *(u32x4*)&Kall[((long)bh * T_LEN + j) * HD + (u ^ (j & 7)) * 8] = o;
  } else {
    int idx = (blk - 5120) * 256 + threadIdx.x;  // 32 * 384 * 64 = 786432
    int hd = idx & 63;
    int t2 = idx >> 6;
    int kb = t2 % 384;  // 8-key block
    int bh = t2 / 384;
    int b = bh >> 4, h = bh & 15;
    int key0 = kb * 8;
    u16 vals[8];
    if (key0 < PREV) {
#pragma unroll
      for (int i = 0; i < 8; ++i)
        vals[i] = f2bf(cache_v[((long)bh * PREV + key0 + i) * HD + hd]);
    } else {
#pragma unroll
      for (int i = 0; i < 8; ++i)
        vals[i] = qkv[((long)(b * S_LEN + key0 + i - PREV)) * (3 * DIM) + 2 * DIM + h * HD + hd];
    }
    u32x4 o;
#pragma unroll
    for (int p = 0; p < 4; ++p)
      o[p] = (u32)vals[2 * p] | ((u32)vals[2 * p + 1] << 16);
    const int span = kb >> 3;
    const int u = (kb & 7) ^ (hd & 7);
    *(u32x4*)&Vtg[((long)bh * HD + hd) * T_LEN + span * 64 + u * 8] = o;
  }
}

// ---------------- flash attention: paired dual-Q blocks, shared KV sweep ----------------
__global__ __launch_bounds__(256, 2) void attn_kernel(const u16* __restrict__ Q,
                                                      const u16* __restrict__ Kg,
                                                      const u16* __restrict__ Vtg,
                                                      u16* __restrict__ ctx, float slope2) {
  __shared__ __align__(16) u16 Ks[2][64 * 64];     // [key][d], swizzled
  __shared__ __align__(16) u16 Vs[2][64 * 64];     // [hd][key], swizzled
  __shared__ __align__(16) u16 Ps[2][4][16 * 64];  // per-qset per-wave P, swizzled

  const int tid = threadIdx.x;
  const int lane = tid & 63;
  const int wv = tid >> 6;
  const int l15 = lane & 15;
  const int lhi = lane >> 4;
  const int c7 = l15 & 7;
  const int bh = blockIdx.x;
  const int p = blockIdx.y;            // pair index 0..15
  const int b = bh >> 4, h = bh & 15;
  const int qA0 = p * 64;
  const int qB0 = (31 - p) * 64;
  const int ntA = 17 + p;              // (PREV + qA0 + 64) >> 6
  const int ntB = 48 - p;              // ntA + ntB = 65

  const long qrowA = (long)bh * S_LEN + qA0 + wv * 16 + l15;
  const long qrowB = (long)bh * S_LEN + qB0 + wv * 16 + l15;
  bf16x8 aqA0 = *(const bf16x8*)&Q[qrowA * HD + lhi * 8];
  bf16x8 aqA1 = *(const bf16x8*)&Q[qrowA * HD + 32 + lhi * 8];
  bf16x8 aqB0 = *(const bf16x8*)&Q[qrowB * HD + lhi * 8];
  bf16x8 aqB1 = *(const bf16x8*)&Q[qrowB * HD + 32 + lhi * 8];

  const long kgb = (long)bh * T_LEN * HD;  // K: [key][64]
  const long vgb = (long)bh * HD * T_LEN;  // Vt: [hd][T]
  const int srow = tid >> 3;               // staging row 0..31
  const int sunit = (tid & 7) * 8;

  const u16* kst = Kg + kgb + (long)srow * HD + sunit;     // +64*HD per tile
  const u16* vst = Vtg + vgb + (long)srow * T_LEN + sunit; // +64 per tile

  // prologue: stage tile 0
  gl_lds16(kst, &Ks[0][tid * 8]);
  gl_lds16(kst + 32 * HD, &Ks[0][2048 + tid * 8]);
  gl_lds16(vst, &Vs[0][tid * 8]);
  gl_lds16(vst + (long)32 * T_LEN, &Vs[0][2048 + tid * 8]);
  kst += 64 * HD;
  vst += 64;
  __syncthreads();

  f32x4 oA[4] = {}, oB[4] = {};
  f32x4 lrunA = {0.f, 0.f, 0.f, 0.f}, lrunB = {0.f, 0.f, 0.f, 0.f};
  float mrunA = -1e30f, mrunB = -1e30f;
  const int qq = wv * 16 + l15;  // local q (mask threshold, same layout both q-sets)

  f32x4 be[4];  // per-thread bias constants slope*(jf*16+4*lhi+r)
#pragma unroll
  for (int jf = 0; jf < 4; ++jf)
#pragma unroll
    for (int r = 0; r < 4; ++r)
      be[jf][r] = slope2 * (float)(jf * 16 + 4 * lhi + r);
  const float bmax = slope2 * 63.f;

  bf16x8 vones;
#pragma unroll
  for (int e = 0; e < 8; ++e) vones[e] = (__bf16)1.0f;

  float ktf = 0.f;
  const float kstep = slope2 * 64.f;

  // softmax + PV for one q-set (separate P buffer per q-set)
  auto process = [&](f32x4 (&sf)[4], bool maskNow, f32x4 (&o)[4], f32x4& lrun,
                     float& mrun, bf16x8 (&vf)[8], u16* Pw) {
    if (maskNow) {
#pragma unroll
      for (int jf = 0; jf < 4; ++jf)
#pragma unroll
        for (int r = 0; r < 4; ++r)
          if (jf * 16 + 4 * lhi + r > qq) sf[jf][r] = -1e30f;
    }
    float h0 = fmaxf(fmaxf(sf[0][0], sf[0][1]), fmaxf(sf[0][2], sf[0][3]));
    float h1 = fmaxf(fmaxf(sf[1][0], sf[1][1]), fmaxf(sf[1][2], sf[1][3]));
    float h2 = fmaxf(fmaxf(sf[2][0], sf[2][1]), fmaxf(sf[2][2], sf[2][3]));
    float h3 = fmaxf(fmaxf(sf[3][0], sf[3][1]), fmaxf(sf[3][2], sf[3][3]));
    float pm = fmaxf(fmaxf(h0, h1), fmaxf(h2, h3));
    pm = fmaxf(pm, __shfl_xor(pm, 16, 64));
    pm = fmaxf(pm, __shfl_xor(pm, 32, 64));
    const float pmax_abs = pm + ktf + bmax;

    if (!__all(pmax_abs - mrun <= 8.f)) {
      const float mnew = fmaxf(mrun, pmax_abs);
      const float scl = exp2f(mrun - mnew);
      mrun = mnew;
#pragma unroll
      for (int r = 0; r < 4; ++r) {
        const float sr = __shfl(scl, 4 * lhi + r, 64);
        lrun[r] *= sr;
#pragma unroll
        for (int hf = 0; hf < 4; ++hf) o[hf][r] *= sr;
      }
    }
    const float meff = mrun - ktf;

#pragma unroll
    for (int jf = 0; jf < 4; ++jf) {
      f32x4 pp;
#pragma unroll
      for (int r = 0; r < 4; ++r)
        pp[r] = exp2f(sf[jf][r] + (be[jf][r] - meff));
      u32x2 pw2;
      pw2[0] = cvtpk(pp[0], pp[1]);
      pw2[1] = cvtpk(pp[2], pp[3]);
      const int u = (2 * jf + (lhi >> 1)) ^ c7;
      *(u32x2*)&Pw[l15 * 64 + u * 8 + (lhi & 1) * 4] = pw2;
    }

    bf16x8 pa0 = *(const bf16x8*)&Pw[l15 * 64 + ((lhi ^ c7) * 8)];
    bf16x8 pa1 = *(const bf16x8*)&Pw[l15 * 64 + (((4 + lhi) ^ c7) * 8)];
    f32x4 psum = {};
    __builtin_amdgcn_s_setprio(1);
    psum = MFMA16(pa0, vones, psum, 0, 0, 0);
    psum = MFMA16(pa1, vones, psum, 0, 0, 0);
#pragma unroll
    for (int hf = 0; hf < 4; ++hf) {
      o[hf] = MFMA16(pa0, vf[2 * hf], o[hf], 0, 0, 0);
      o[hf] = MFMA16(pa1, vf[2 * hf + 1], o[hf], 0, 0, 0);
    }
    __builtin_amdgcn_s_setprio(0);
    lrun += psum;
  };

  for (int t = 0; t < ntB; ++t) {
    const int cur = t & 1, nxt = cur ^ 1;
    const bool lastStage = (t + 1 == ntB);
    if (!lastStage) {
      gl_lds16(kst, &Ks[nxt][tid * 8]);
      gl_lds16(kst + 32 * HD, &Ks[nxt][2048 + tid * 8]);
      gl_lds16(vst, &Vs[nxt][tid * 8]);
      gl_lds16(vst + (long)32 * T_LEN, &Vs[nxt][2048 + tid * 8]);
      kst += 64 * HD;
      vst += 64;
    }
    const bool actA = (t < ntA);

    // K fragments once, shared by both q-sets
    bf16x8 kf[8];
#pragma unroll
    for (int jf = 0; jf < 4; ++jf) {
      const int krow = jf * 16 + l15;
      kf[2 * jf] = *(const bf16x8*)&Ks[cur][krow * 64 + ((lhi ^ c7) * 8)];
      kf[2 * jf + 1] = *(const bf16x8*)&Ks[cur][krow * 64 + (((4 + lhi) ^ c7) * 8)];
    }
    // V fragments once, shared by both q-sets
    bf16x8 vf[8];
#pragma unroll
    for (int hf = 0; hf < 4; ++hf) {
      const int vrow = hf * 16 + l15;
      vf[2 * hf] = *(const bf16x8*)&Vs[cur][vrow * 64 + ((lhi ^ c7) * 8)];
      vf[2 * hf + 1] = *(const bf16x8*)&Vs[cur][vrow * 64 + (((4 + lhi) ^ c7) * 8)];
    }

    // QK^T for both q-sets
    f32x4 sB[4], sA[4];
    __builtin_amdgcn_s_setprio(1);
#pragma unroll
    for (int jf = 0; jf < 4; ++jf) {
      f32x4 s = {};
      s = MFMA16(kf[2 * jf], aqB0, s, 0, 0, 0);
      s = MFMA16(kf[2 * jf + 1], aqB1, s, 0, 0, 0);
      sB[jf] = s;
    }
    __builtin_amdgcn_s_setprio(0);
    if (actA) {
      __builtin_amdgcn_s_setprio(1);
#pragma unroll
      for (int jf = 0; jf < 4; ++jf) {
        f32x4 s = {};
        s = MFMA16(kf[2 * jf], aqA0, s, 0, 0, 0);
        s = MFMA16(kf[2 * jf + 1], aqA1, s, 0, 0, 0);
        sA[jf] = s;
      }
      __builtin_amdgcn_s_setprio(0);
    }

    process(sB, t == ntB - 1, oB, lrunB, mrunB, vf, &Ps[0][wv][0]);
    if (actA) process(sA, t == ntA - 1, oA, lrunA, mrunA, vf, &Ps[1][wv][0]);

    ktf += kstep;
    if (!lastStage) __syncthreads();
  }

  // epilogue: rows q_local = 4*lhi + r; cols hd = hf*16 + l15
#pragma unroll
  for (int r = 0; r < 4; ++r) {
    const float invA = 1.f / lrunA[r];
    const float invB = 1.f / lrunB[r];
    const long rowA = (long)b * S_LEN + qA0 + wv * 16 + 4 * lhi + r;
    const long rowB = (long)b * S_LEN + qB0 + wv * 16 + 4 * lhi + r;
#pragma unroll
    for (int hf = 0; hf < 4; ++hf) {
      ctx[rowA * DIM + h * HD + hf * 16 + l15] = f2bf(oA[hf][r] * invA);
      ctx[rowB * DIM + h * HD + hf * 16 + l15] = f2bf(oB[hf][r] * invB);
    }
  }
}

// ---------------------------------------------------------------------------
extern "C" void kernel_launch(void* const* d_in, const int* in_sizes, int n_in,
                              void* d_out, int out_size, void* d_ws, size_t ws_size,
                              hipStream_t stream) {
  (void)in_sizes; (void)n_in; (void)out_size; (void)ws_size;
  const float* x       = (const float*)d_in[0];
  const float* cache_k = (const float*)d_in[1];
  const float* cache_v = (const float*)d_in[2];
  const float* cosT    = (const float*)d_in[3];
  const float* sinT    = (const float*)d_in[4];
  const float* attn_w  = (const float*)d_in[5];
  const float* ffn_w   = (const float*)d_in[6];
  const float* wq      = (const float*)d_in[7];
  const float* bq      = (const float*)d_in[8];
  const float* wk      = (const float*)d_in[9];
  const float* bk      = (const float*)d_in[10];
  const float* wv_     = (const float*)d_in[11];
  const float* bv      = (const float*)d_in[12];
  const float* wo      = (const float*)d_in[13];
  const float* bo      = (const float*)d_in[14];
  const float* wg      = (const float*)d_in[15];
  const float* bg      = (const float*)d_in[16];
  const float* wval    = (const float*)d_in[17];
  const float* bval    = (const float*)d_in[18];
  const float* wp      = (const float*)d_in[19];
  const float* bp      = (const float*)d_in[20];
  float* out = (float*)d_out;

  char* w = (char*)d_ws;
  size_t off = 0;
  auto alloc = [&](size_t bytes) -> char* {
    char* p = w + off;
    off += (bytes + 255) & ~(size_t)255;
    return p;
  };
  // permanent
  u16*   wqkv_bf  = (u16*)alloc((size_t)3 * DIM * DIM * 2);  // preswizzled
  u16*   wo_bf    = (u16*)alloc((size_t)DIM * DIM * 2);      // linear
  u16*   wgv_bf   = (u16*)alloc((size_t)2 * FF * DIM * 2);   // interleaved+preswizzled
  u16*   wproj_bf = (u16*)alloc((size_t)DIM * FF * 2);       // linear
  float* bqkv     = (float*)alloc((size_t)3 * DIM * 4);
  float* bgv      = (float*)alloc((size_t)2 * FF * 4);       // interleaved
  float* x2       = (float*)alloc((size_t)MROWS * DIM * 4);
  // arena with lifetime-based aliasing
  char* AR = alloc((size_t)117440512);
  u16* qkv   = (u16*)(AR + 0);          // [4096][3072]   live: qkv gemm -> rope/build
  u16* Qb    = (u16*)(AR + 25165824);   // [32][2048][64] live: rope -> attn
  u16* Kb    = (u16*)(AR + 33554432);   // [32][3072][64]
  u16* Vtg   = (u16*)(AR + 46137344);   // [32][64][3072] transposed V
  u16* h1    = (u16*)(AR + 58720256);   // [4096][1024]   preswizzled (qkv gemm A)
  u16* ctx   = (u16*)(AR + 0);          // [4096][1024]   linear (aliases dead qkv)
  u16* h2    = (u16*)(AR + 8388608);    // [4096][1024]   preswizzled (gv gemm A)
  u16* gated = (u16*)(AR + 16777216);   // [4096][4096]   linear

  // 1) ALL weight + bias conversion in one launch
  cvt_all_kernel<<<6172, 256, 0, stream>>>(wq, wk, wv_, wg, wval, wo, wp,
                                           bq, bk, bv, bg, bval,
                                           wqkv_bf, wgv_bf, wo_bf, wproj_bf,
                                           bqkv, bgv);

  // 2) attn rmsnorm (swizzled out), fused QKV 256-gemm
  rmsnorm_kernel<<<MROWS, 256, 0, stream>>>(x, attn_w, h1);
  gemm256<0><<<dim3(12, 16), 512, 0, stream>>>(h1, wqkv_bf, bqkv, qkv, 3 * DIM, DIM);
  // 3) fused rope + cache concat (1 launch)
  rope_all_kernel<<<8192, 256, 0, stream>>>(qkv, cache_k, cache_v, cosT, sinT,
                                            Qb, Kb, Vtg);
  // 4) attention: paired dual-Q blocks
  attn_kernel<<<dim3(B_SZ * NH, 16), 256, 0, stream>>>(
      Qb, Kb, Vtg, ctx, (2.0f / (float)(T_LEN - 1)) * LOG2E);
  // 5) o-proj + residual (fp32), skinny tile
  gemm_bt<1, 64><<<dim3(16, 32), 256, 0, stream>>>(ctx, wo_bf, bo, x, nullptr, x2,
                                                   DIM, DIM);
  // 6) ffn rmsnorm (swizzled out), gate+value 256-gemm w/ silu epilogue, proj + residual
  rmsnorm_kernel<<<MROWS, 256, 0, stream>>>(x2, ffn_w, h2);
  gemm256<2><<<dim3(32, 16), 512, 0, stream>>>(h2, wgv_bf, bgv, gated, 2 * FF, DIM);
  gemm_bt<1, 64><<<dim3(16, 32), 256, 0, stream>>>(gated, wproj_bf, bp, x2, nullptr, out,
                                                   DIM, FF);
}

// Round 13
// 347.268 us; speedup vs baseline: 1.0167x; 1.0071x over previous
//
#include <hip/hip_runtime.h>
#include <stdint.h>

typedef unsigned short u16;
typedef unsigned int   u32;
typedef __bf16 bf16x8 __attribute__((ext_vector_type(8)));
typedef float  f32x4  __attribute__((ext_vector_type(4)));
typedef u32    u32x4  __attribute__((ext_vector_type(4)));
typedef u32    u32x2  __attribute__((ext_vector_type(2)));

#define B_SZ  2
#define S_LEN 2048
#define NH    16
#define HD    64
#define DIM   1024
#define FF    4096
#define T_LEN 3072
#define PREV  1024
#define MROWS (B_SZ * S_LEN) /* 4096 */
#define LOG2E 1.44269504f

#define MFMA16 __builtin_amdgcn_mfma_f32_16x16x32_bf16

__device__ __forceinline__ u16 f2bf(float f) {
  u32 u = __builtin_bit_cast(u32, f);
  u32 r = u + 0x7FFFu + ((u >> 16) & 1u);
  return (u16)(r >> 16);
}
__device__ __forceinline__ float bf2f(u16 h) {
  u32 u = ((u32)h) << 16;
  return __builtin_bit_cast(float, u);
}
__device__ __forceinline__ u32 cvtpk(float lo, float hi) {
  u32 r;
  asm("v_cvt_pk_bf16_f32 %0, %1, %2" : "=v"(r) : "v"(lo), "v"(hi));
  return r;
}

// async global->LDS, 16B per lane. LDS dest must be wave-uniform base + lane*16.
__device__ __forceinline__ void gl_lds16(const void* g, void* l) {
  __builtin_amdgcn_global_load_lds(
      (const __attribute__((address_space(1))) u32*)g,
      (__attribute__((address_space(3))) u32*)l, 16, 0, 0);
}

#define GFENCE() asm volatile("" ::: "memory")
#define BARF()                         \
  do {                                 \
    GFENCE();                          \
    __builtin_amdgcn_s_barrier();      \
    GFENCE();                          \
  } while (0)

// ---------------- ALL weight/bias conversion in ONE launch ----------------
__global__ __launch_bounds__(256) void cvt_all_kernel(
    const float* __restrict__ wq, const float* __restrict__ wk,
    const float* __restrict__ wv, const float* __restrict__ wg,
    const float* __restrict__ wval, const float* __restrict__ wo,
    const float* __restrict__ wp, const float* __restrict__ bq,
    const float* __restrict__ bk, const float* __restrict__ bv,
    const float* __restrict__ bg, const float* __restrict__ bval,
    u16* __restrict__ wqkv_bf, u16* __restrict__ wgv_bf,
    u16* __restrict__ wo_bf, u16* __restrict__ wp_bf,
    float* __restrict__ bqkv, float* __restrict__ bgv) {
  long gid = (long)blockIdx.x * 256 + threadIdx.x;
  if (gid < 393216) {  // wqkv, K-unit XOR-preswizzled
    int i = (int)gid;
    const int seg = i >> 17;
    const int loc = i & 131071;
    const float* src = (seg == 0) ? wq : (seg == 1) ? wk : wv;
    int row = loc >> 7;
    int g = loc & 127;
    const float* s = &src[((long)row << 10) + g * 8];
    f32x4 a = *(const f32x4*)s;
    f32x4 b = *(const f32x4*)(s + 4);
    u32x4 o;
    o[0] = (u32)f2bf(a[0]) | ((u32)f2bf(a[1]) << 16);
    o[1] = (u32)f2bf(a[2]) | ((u32)f2bf(a[3]) << 16);
    o[2] = (u32)f2bf(b[0]) | ((u32)f2bf(b[1]) << 16);
    o[3] = (u32)f2bf(b[2]) | ((u32)f2bf(b[3]) << 16);
    const int gp = (g & ~7) | ((g & 7) ^ (row & 7));
    *(u32x4*)&wqkv_bf[((long)seg << 20) + ((long)row << 10) + gp * 8] = o;
    return;
  }
  gid -= 393216;
  if (gid < 524288) {  // wgv interleave + preswizzle
    int i = (int)gid;
    int j = i >> 7;
    int g = i & 127;
    const float* sg = &wg[((long)j << 10) + g * 8];
    const float* sv = &wval[((long)j << 10) + g * 8];
    f32x4 a = *(const f32x4*)sg;
    f32x4 b = *(const f32x4*)(sg + 4);
    u32x4 og;
    og[0] = (u32)f2bf(a[0]) | ((u32)f2bf(a[1]) << 16);
    og[1] = (u32)f2bf(a[2]) | ((u32)f2bf(a[3]) << 16);
    og[2] = (u32)f2bf(b[0]) | ((u32)f2bf(b[1]) << 16);
    og[3] = (u32)f2bf(b[2]) | ((u32)f2bf(b[3]) << 16);
    f32x4 c = *(const f32x4*)sv;
    f32x4 d = *(const f32x4*)(sv + 4);
    u32x4 ov;
    ov[0] = (u32)f2bf(c[0]) | ((u32)f2bf(c[1]) << 16);
    ov[1] = (u32)f2bf(c[2]) | ((u32)f2bf(c[3]) << 16);
    ov[2] = (u32)f2bf(d[0]) | ((u32)f2bf(d[1]) << 16);
    ov[3] = (u32)f2bf(d[2]) | ((u32)f2bf(d[3]) << 16);
    const int rg = 2 * j, rv = 2 * j + 1;
    const int gpg = (g & ~7) | ((g & 7) ^ (rg & 7));
    const int gpv = (g & ~7) | ((g & 7) ^ (rv & 7));
    *(u32x4*)&wgv_bf[((long)rg << 10) + gpg * 8] = og;
    *(u32x4*)&wgv_bf[((long)rv << 10) + gpv * 8] = ov;
    return;
  }
  gid -= 524288;
  if (gid < 131072) {  // wo linear
    int i = (int)gid;
    f32x4 a = *(const f32x4*)&wo[(long)i * 8];
    f32x4 b = *(const f32x4*)&wo[(long)i * 8 + 4];
    u32x4 o;
    o[0] = (u32)f2bf(a[0]) | ((u32)f2bf(a[1]) << 16);
    o[1] = (u32)f2bf(a[2]) | ((u32)f2bf(a[3]) << 16);
    o[2] = (u32)f2bf(b[0]) | ((u32)f2bf(b[1]) << 16);
    o[3] = (u32)f2bf(b[2]) | ((u32)f2bf(b[3]) << 16);
    *(u32x4*)&wo_bf[(long)i * 8] = o;
    return;
  }
  gid -= 131072;
  if (gid < 524288) {  // wp linear
    int i = (int)gid;
    f32x4 a = *(const f32x4*)&wp[(long)i * 8];
    f32x4 b = *(const f32x4*)&wp[(long)i * 8 + 4];
    u32x4 o;
    o[0] = (u32)f2bf(a[0]) | ((u32)f2bf(a[1]) << 16);
    o[1] = (u32)f2bf(a[2]) | ((u32)f2bf(a[3]) << 16);
    o[2] = (u32)f2bf(b[0]) | ((u32)f2bf(b[1]) << 16);
    o[3] = (u32)f2bf(b[2]) | ((u32)f2bf(b[3]) << 16);
    *(u32x4*)&wp_bf[(long)i * 8] = o;
    return;
  }
  gid -= 524288;
  {  // bias packs
    int i = (int)gid;
    if (i < 3 * DIM) {
      float v = (i < DIM) ? bq[i] : (i < 2 * DIM) ? bk[i - DIM] : bv[i - 2 * DIM];
      bqkv[i] = v;
    } else if (i < 3 * DIM + FF) {
      int j = i - 3 * DIM;
      bgv[2 * j] = bg[j];
      bgv[2 * j + 1] = bval[j];
    }
  }
}

// ---------------- RMSNorm: fp32 row -> bf16 row, K-unit XOR-preswizzled out ----------------
__global__ __launch_bounds__(256) void rmsnorm_kernel(const float* __restrict__ x,
                                                      const float* __restrict__ w,
                                                      u16* __restrict__ out) {
  const int row = blockIdx.x;
  const int tid = threadIdx.x;
  const long base = (long)row * DIM + tid * 4;
  f32x4 v = *(const f32x4*)&x[base];
  float ss = v[0] * v[0] + v[1] * v[1] + v[2] * v[2] + v[3] * v[3];
#pragma unroll
  for (int d = 1; d <= 32; d <<= 1) ss += __shfl_xor(ss, d, 64);
  __shared__ float red[4];
  if ((tid & 63) == 0) red[tid >> 6] = ss;
  __syncthreads();
  float tot = red[0] + red[1] + red[2] + red[3];
  const float sc = rsqrtf(tot * (1.f / (float)DIM) + 1e-6f);
  f32x4 wv4 = *(const f32x4*)&w[tid * 4];
  u32x2 o;
  o[0] = (u32)f2bf(v[0] * sc * wv4[0]) | ((u32)f2bf(v[1] * sc * wv4[1]) << 16);
  o[1] = (u32)f2bf(v[2] * sc * wv4[2]) | ((u32)f2bf(v[3] * sc * wv4[3]) << 16);
  const int u = tid >> 1, hf = tid & 1;
  const int up = (u & 0x78) | ((u & 7) ^ (row & 7));
  *(u32x2*)&out[(long)row * DIM + up * 8 + hf * 4] = o;
}

// ---------------- 256x256 GEMM, 2-barrier K-tile (r9 best), K multiple of 64 ----------
template <int EPI>
__global__ __launch_bounds__(512, 2) void gemm256(const u16* __restrict__ A,
                                                  const u16* __restrict__ Bw,
                                                  const float* __restrict__ bias,
                                                  u16* __restrict__ out_bf,
                                                  int N, int K) {
  __shared__ __align__(16) u16 Ab[2][256 * 64];
  __shared__ __align__(16) u16 Bb[2][256 * 64];
  const int tid = threadIdx.x;
  const int lane = tid & 63;
  const int wid = tid >> 6;
  const int wm = wid >> 2, wn = wid & 3;
  const int l15 = lane & 15, lhi = lane >> 4;
  const int c7 = l15 & 7;
  const long m0 = (long)blockIdx.y * 256;
  const long n0 = (long)blockIdx.x * 256;
  const int NT = K >> 6;

  const int srow = tid >> 3;
  const int sunit = (tid & 7) * 8;
  const u16* agp = A + (m0 + srow) * K + sunit;
  const u16* bgp = Bw + (n0 + srow) * K + sunit;
  const int ldst = tid * 8;

  auto stageA = [&](int kt, int b) {
    const int k0 = kt << 6;
    u16* d = &Ab[b][0];
#pragma unroll
    for (int c = 0; c < 4; ++c)
      gl_lds16(agp + (long)(c * 64) * K + k0, d + c * 4096 + ldst);
  };
  auto stageB = [&](int kt, int b) {
    const int k0 = kt << 6;
    u16* d = &Bb[b][0];
#pragma unroll
    for (int c = 0; c < 4; ++c)
      gl_lds16(bgp + (long)(c * 64) * K + k0, d + c * 4096 + ldst);
  };

#define READ_A(MH)                                                               \
  _Pragma("unroll") for (int m_ = 0; m_ < 4; ++m_) {                             \
    _Pragma("unroll") for (int ks_ = 0; ks_ < 2; ++ks_) {                        \
      Afr[MH][m_ * 2 + ks_] =                                                    \
          *(const bf16x8*)&Ac[(wm * 128 + (MH)*64 + m_ * 16 + l15) * 64 +        \
                              (((ks_ * 4 + lhi) ^ c7) * 8)];                     \
    }                                                                            \
  }
#define READ_B(NH)                                                               \
  _Pragma("unroll") for (int n_ = 0; n_ < 2; ++n_) {                             \
    _Pragma("unroll") for (int ks_ = 0; ks_ < 2; ++ks_) {                        \
      Bfr[NH][n_ * 2 + ks_] =                                                    \
          *(const bf16x8*)&Bc[(wn * 64 + (NH)*32 + n_ * 16 + l15) * 64 +         \
                              (((ks_ * 4 + lhi) ^ c7) * 8)];                     \
    }                                                                            \
  }
#define QUAD(MH, NH)                                                             \
  do {                                                                           \
    __builtin_amdgcn_s_setprio(1);                                               \
    _Pragma("unroll") for (int m_ = 0; m_ < 4; ++m_) {                           \
      _Pragma("unroll") for (int n_ = 0; n_ < 2; ++n_) {                         \
        acc[(MH)*4 + m_][(NH)*2 + n_] =                                          \
            MFMA16(Afr[MH][m_ * 2], Bfr[NH][n_ * 2],                             \
                   acc[(MH)*4 + m_][(NH)*2 + n_], 0, 0, 0);                      \
        acc[(MH)*4 + m_][(NH)*2 + n_] =                                          \
            MFMA16(Afr[MH][m_ * 2 + 1], Bfr[NH][n_ * 2 + 1],                     \
                   acc[(MH)*4 + m_][(NH)*2 + n_], 0, 0, 0);                      \
      }                                                                          \
    }                                                                            \
    __builtin_amdgcn_s_setprio(0);                                               \
  } while (0)

  f32x4 acc[8][4] = {};

  // prologue: tiles 0,1 staged; wait tile 0 (tile 1 stays in flight)
  stageA(0, 0);
  stageB(0, 0);
  stageA(1, 1);
  stageB(1, 1);
  asm volatile("s_waitcnt vmcnt(8)" ::: "memory");
  __builtin_amdgcn_s_barrier();
  GFENCE();

  for (int kt = 0; kt < NT; ++kt) {
    const int b = kt & 1;
    const u16* Ac = &Ab[b][0];
    const u16* Bc = &Bb[b][0];
    bf16x8 Afr[2][8], Bfr[2][4];
    // read everything for this tile (24 ds_read_b128), overlap with first 32 MFMA
    READ_A(0);
    READ_B(0);
    READ_A(1);
    READ_B(1);
    QUAD(0, 0);
    QUAD(1, 0);  // B-half0 dead after this
    // all this tile's LDS reads sampled before anyone overwrites buf b
    asm volatile("s_waitcnt lgkmcnt(0)" ::: "memory");
    __builtin_amdgcn_sched_barrier(0);
    __builtin_amdgcn_s_barrier();
    GFENCE();
    if (kt + 2 < NT) {
      stageA(kt + 2, b);
      stageB(kt + 2, b);
    }
    QUAD(0, 1);
    QUAD(1, 1);
    // boundary: tile kt+1 must be resident; keep kt+2 prefetch in flight
    if (kt + 1 < NT) {
      if (kt + 2 < NT)
        asm volatile("s_waitcnt vmcnt(8)" ::: "memory");
      else
        asm volatile("s_waitcnt vmcnt(0)" ::: "memory");
      __builtin_amdgcn_s_barrier();
      GFENCE();
    }
  }
#undef READ_A
#undef READ_B
#undef QUAD

#pragma unroll
  for (int mi = 0; mi < 8; ++mi) {
    const long row0 = m0 + wm * 128 + mi * 16 + lhi * 4;
#pragma unroll
    for (int ni = 0; ni < 4; ++ni) {
      const long col = n0 + wn * 64 + ni * 16 + l15;
      const float bb = bias[col];
#pragma unroll
      for (int r = 0; r < 4; ++r) {
        float v = acc[mi][ni][r] + bb;
        if (EPI == 2) {
          float other = __shfl_xor(v, 1, 64);
          if (!(l15 & 1)) {
            float s = v / (1.f + __expf(-v)) * other;  // silu(g)*v
            out_bf[(row0 + r) * (N >> 1) + (col >> 1)] = f2bf(s);
          }
        } else {
          out_bf[(row0 + r) * N + col] = f2bf(v);
        }
      }
    }
  }
}

// ---------------- 3-buffer GEMM (linear layouts) for skinny N ----------------
template <int EPI, int NB>
__global__ __launch_bounds__(256) void gemm_bt(const u16* __restrict__ A,
                                               const u16* __restrict__ Bw,
                                               const float* __restrict__ bias,
                                               const float* __restrict__ resid,
                                               u16* __restrict__ out_bf,
                                               float* __restrict__ out_f,
                                               int N, int K) {
  constexpr int BHALF = NB / 64;
  constexpr int NFR = NB / 32;
  constexpr int LPT = 2 + BHALF;
  __shared__ __align__(16) u16 As[3][128 * 32];
  __shared__ __align__(16) u16 Bs[3][NB * 32];
  const int tid = threadIdx.x;
  const int lane = tid & 63;
  const int wv = tid >> 6;
  const int wr = wv >> 1, wc = wv & 1;
  const long m0 = (long)blockIdx.y * 128;
  const long n0 = (long)blockIdx.x * NB;

  const int arow = tid >> 2;
  const int acol = (tid & 3) << 3;
  const u16* ag = A + (m0 + arow) * K + acol;
  const u16* bg = Bw + (n0 + arow) * K + acol;
  const long hK = (long)64 * K;

  f32x4 acc[4][NFR] = {};
  const int l15 = lane & 15;
  const int lhi = lane >> 4;
  const int aoff0 = (wr * 64 + l15) * 32 + lhi * 8;
  const int boff0 = (wc * (NB / 2) + l15) * 32 + lhi * 8;
  const int nk = K >> 5;

  auto stage = [&](int t, int buf) {
    const int k0 = t << 5;
    gl_lds16(ag + k0, &As[buf][tid * 8]);
    gl_lds16(ag + k0 + hK, &As[buf][2048 + tid * 8]);
    gl_lds16(bg + k0, &Bs[buf][tid * 8]);
    if (BHALF == 2) gl_lds16(bg + k0 + hK, &Bs[buf][2048 + tid * 8]);
  };

  stage(0, 0);
  stage(1, 1);
  asm volatile("s_waitcnt vmcnt(%0)" ::"n"(LPT) : "memory");
  __builtin_amdgcn_s_barrier();
  GFENCE();

  for (int t = 0; t < nk; ++t) {
    const int cb = t % 3;
    if (t + 2 < nk) stage(t + 2, (t + 2) % 3);
    bf16x8 af[4], bfr[NFR];
#pragma unroll
    for (int i = 0; i < 4; ++i) af[i] = *(const bf16x8*)&As[cb][aoff0 + i * 16 * 32];
#pragma unroll
    for (int j = 0; j < NFR; ++j) bfr[j] = *(const bf16x8*)&Bs[cb][boff0 + j * 16 * 32];
    __builtin_amdgcn_s_setprio(1);
#pragma unroll
    for (int i = 0; i < 4; ++i)
#pragma unroll
      for (int j = 0; j < NFR; ++j)
        acc[i][j] = MFMA16(af[i], bfr[j], acc[i][j], 0, 0, 0);
    __builtin_amdgcn_s_setprio(0);
    if (t + 2 < nk) {
      asm volatile("s_waitcnt vmcnt(%0)" ::"n"(LPT) : "memory");
      __builtin_amdgcn_s_barrier();
      GFENCE();
    } else if (t + 1 < nk) {
      asm volatile("s_waitcnt vmcnt(0)" ::: "memory");
      __builtin_amdgcn_s_barrier();
      GFENCE();
    }
  }

#pragma unroll
  for (int i = 0; i < 4; ++i) {
    const long row0 = m0 + wr * 64 + i * 16 + lhi * 4;
#pragma unroll
    for (int j = 0; j < NFR; ++j) {
      const long col = n0 + wc * (NB / 2) + j * 16 + l15;
      const float bb = bias[col];
#pragma unroll
      for (int r = 0; r < 4; ++r) {
        const long idx = (row0 + r) * N + col;
        float v = acc[i][j][r] + bb;
        if (EPI == 0) out_bf[idx] = f2bf(v);
        else          out_f[idx] = resid[idx] + v;
      }
    }
  }
}

// ---------------- fused RoPE(Q), RoPE(K)+concat, V-transpose+concat ----------------
// blocks [0,2048): Q; [2048,5120): K; [5120,8192): Vt
__global__ __launch_bounds__(256) void rope_all_kernel(const u16* __restrict__ qkv,
                                                       const float* __restrict__ cache_k,
                                                       const float* __restrict__ cache_v,
                                                       const float* __restrict__ cosT,
                                                       const float* __restrict__ sinT,
                                                       u16* __restrict__ Q,
                                                       u16* __restrict__ Kall,
                                                       u16* __restrict__ Vtg) {
  const int blk = blockIdx.x;
  if (blk < 2048) {
    int idx = blk * 256 + threadIdx.x;  // B*H*S*8 = 524288 units of 8 elems
    int u = idx & 7;
    int s = (idx >> 3) & (S_LEN - 1);
    int bh = idx >> 14;
    int b = bh >> 4, h = bh & 15;
    int pos = PREV + s;
    const float SC = 0.125f * LOG2E;
    const u16* src = qkv + ((long)(b * S_LEN + s)) * (3 * DIM) + h * HD + u * 8;
    u32x4 d = *(const u32x4*)src;
    f32x4 cv = *(const f32x4*)&cosT[(long)pos * 32 + u * 4];
    f32x4 sv = *(const f32x4*)&sinT[(long)pos * 32 + u * 4];
    u32x4 o;
#pragma unroll
    for (int p = 0; p < 4; ++p) {
      float x0 = bf2f((u16)(d[p] & 0xffff));
      float x1 = bf2f((u16)(d[p] >> 16));
      float y0 = (x0 * cv[p] - x1 * sv[p]) * SC;
      float y1 = (x0 * sv[p] + x1 * cv[p]) * SC;
      o[p] = (u32)f2bf(y0) | ((u32)f2bf(y1) << 16);
    }
    *(u32x4*)&Q[((long)bh * S_LEN + s) * HD + u * 8] = o;
  } else if (blk < 5120) {
    int idx = (blk - 2048) * 256 + threadIdx.x;  // B*H*T*8 = 786432
    int u = idx & 7;
    int t2 = idx >> 3;
    int j = t2 % T_LEN;
    int bh = t2 / T_LEN;
    int b = bh >> 4, h = bh & 15;
    float e[8];
    if (j < PREV) {
      const float* src = cache_k + ((long)bh * PREV + j) * HD + u * 8;
      f32x4 a = *(const f32x4*)src;
      f32x4 c = *(const f32x4*)(src + 4);
      e[0] = a[0]; e[1] = a[1]; e[2] = a[2]; e[3] = a[3];
      e[4] = c[0]; e[5] = c[1]; e[6] = c[2]; e[7] = c[3];
    } else {
      const u16* src = qkv + ((long)(b * S_LEN + (j - PREV))) * (3 * DIM) + DIM + h * HD + u * 8;
      u32x4 d = *(const u32x4*)src;
#pragma unroll
      for (int p = 0; p < 4; ++p) {
        e[2 * p] = bf2f((u16)(d[p] & 0xffff));
        e[2 * p + 1] = bf2f((u16)(d[p] >> 16));
      }
    }
    f32x4 cv = *(const f32x4*)&cosT[(long)j * 32 + u * 4];
    f32x4 sv = *(const f32x4*)&sinT[(long)j * 32 + u * 4];
    u32x4 o;
#pragma unroll
    for (int p = 0; p < 4; ++p) {
      float y0 = e[2 * p] * cv[p] - e[2 * p + 1] * sv[p];
      float y1 = e[2 * p] * sv[p] + e[2 * p + 1] * cv[p];
      o[p] = (u32)f2bf(y0) | ((u32)f2bf(y1) << 16);
    }
    *(u32x4*)&Kall[((long)bh * T_LEN + j) * HD + (u ^ (j & 7)) * 8] = o;
  } else {
    int idx = (blk - 5120) * 256 + threadIdx.x;  // 32 * 384 * 64 = 786432
    int hd = idx & 63;
    int t2 = idx >> 6;
    int kb = t2 % 384;  // 8-key block
    int bh = t2 / 384;
    int b = bh >> 4, h = bh & 15;
    int key0 = kb * 8;
    u16 vals[8];
    if (key0 < PREV) {
#pragma unroll
      for (int i = 0; i < 8; ++i)
        vals[i] = f2bf(cache_v[((long)bh * PREV + key0 + i) * HD + hd]);
    } else {
#pragma unroll
      for (int i = 0; i < 8; ++i)
        vals[i] = qkv[((long)(b * S_LEN + key0 + i - PREV)) * (3 * DIM) + 2 * DIM + h * HD + hd];
    }
    u32x4 o;
#pragma unroll
    for (int p = 0; p < 4; ++p)
      o[p] = (u32)vals[2 * p] | ((u32)vals[2 * p + 1] << 16);
    const int span = kb >> 3;
    const int u = (kb & 7) ^ (hd & 7);
    *(u32x4*)&Vtg[((long)bh * HD + hd) * T_LEN + span * 64 + u * 8] = o;
  }
}

// ---------------- flash attention: paired dual-Q, 4-buffer KV, sync every 2 tiles ----
// Syncs only after odd t bound wave skew to a 2-tile window; bufs staged in the window
// were last read >=2 tiles before the governing sync (WAR), and every buf read in the
// window was staged before that sync's vmcnt(0) drain (RAW, cross-wave safe).
__global__ __launch_bounds__(256, 2) void attn_kernel(const u16* __restrict__ Q,
                                                      const u16* __restrict__ Kg,
                                                      const u16* __restrict__ Vtg,
                                                      u16* __restrict__ ctx, float slope2) {
  __shared__ __align__(16) u16 Ks[4][64 * 64];     // [key][d], swizzled
  __shared__ __align__(16) u16 Vs[4][64 * 64];     // [hd][key], swizzled
  __shared__ __align__(16) u16 Ps[2][4][16 * 64];  // per-qset per-wave P, swizzled

  const int tid = threadIdx.x;
  const int lane = tid & 63;
  const int wv = tid >> 6;
  const int l15 = lane & 15;
  const int lhi = lane >> 4;
  const int c7 = l15 & 7;
  const int bh = blockIdx.x;
  const int p = blockIdx.y;            // pair index 0..15
  const int b = bh >> 4, h = bh & 15;
  const int qA0 = p * 64;
  const int qB0 = (31 - p) * 64;
  const int ntA = 17 + p;              // (PREV + qA0 + 64) >> 6
  const int ntB = 48 - p;              // ntA + ntB = 65

  const long qrowA = (long)bh * S_LEN + qA0 + wv * 16 + l15;
  const long qrowB = (long)bh * S_LEN + qB0 + wv * 16 + l15;
  bf16x8 aqA0 = *(const bf16x8*)&Q[qrowA * HD + lhi * 8];
  bf16x8 aqA1 = *(const bf16x8*)&Q[qrowA * HD + 32 + lhi * 8];
  bf16x8 aqB0 = *(const bf16x8*)&Q[qrowB * HD + lhi * 8];
  bf16x8 aqB1 = *(const bf16x8*)&Q[qrowB * HD + 32 + lhi * 8];

  const long kgb = (long)bh * T_LEN * HD;  // K: [key][64]
  const long vgb = (long)bh * HD * T_LEN;  // Vt: [hd][T]
  const int srow = tid >> 3;               // staging row 0..31
  const int sunit = (tid & 7) * 8;

  const u16* kst = Kg + kgb + (long)srow * HD + sunit;     // +64*HD per staged tile
  const u16* vst = Vtg + vgb + (long)srow * T_LEN + sunit; // +64 per staged tile

  // prologue: stage tiles 0 and 1 (ntB >= 33 always)
  gl_lds16(kst, &Ks[0][tid * 8]);
  gl_lds16(kst + 32 * HD, &Ks[0][2048 + tid * 8]);
  gl_lds16(vst, &Vs[0][tid * 8]);
  gl_lds16(vst + (long)32 * T_LEN, &Vs[0][2048 + tid * 8]);
  kst += 64 * HD;
  vst += 64;
  gl_lds16(kst, &Ks[1][tid * 8]);
  gl_lds16(kst + 32 * HD, &Ks[1][2048 + tid * 8]);
  gl_lds16(vst, &Vs[1][tid * 8]);
  gl_lds16(vst + (long)32 * T_LEN, &Vs[1][2048 + tid * 8]);
  kst += 64 * HD;
  vst += 64;
  __syncthreads();

  f32x4 oA[4] = {}, oB[4] = {};
  f32x4 lrunA = {0.f, 0.f, 0.f, 0.f}, lrunB = {0.f, 0.f, 0.f, 0.f};
  float mrunA = -1e30f, mrunB = -1e30f;
  const int qq = wv * 16 + l15;  // local q (mask threshold, same layout both q-sets)

  f32x4 be[4];  // per-thread bias constants slope*(jf*16+4*lhi+r)
#pragma unroll
  for (int jf = 0; jf < 4; ++jf)
#pragma unroll
    for (int r = 0; r < 4; ++r)
      be[jf][r] = slope2 * (float)(jf * 16 + 4 * lhi + r);
  const float bmax = slope2 * 63.f;

  bf16x8 vones;
#pragma unroll
  for (int e = 0; e < 8; ++e) vones[e] = (__bf16)1.0f;

  float ktf = 0.f;
  const float kstep = slope2 * 64.f;

  // softmax + PV for one q-set (separate P buffer per q-set)
  auto process = [&](f32x4 (&sf)[4], bool maskNow, f32x4 (&o)[4], f32x4& lrun,
                     float& mrun, bf16x8 (&vf)[8], u16* Pw) {
    if (maskNow) {
#pragma unroll
      for (int jf = 0; jf < 4; ++jf)
#pragma unroll
        for (int r = 0; r < 4; ++r)
          if (jf * 16 + 4 * lhi + r > qq) sf[jf][r] = -1e30f;
    }
    float h0 = fmaxf(fmaxf(sf[0][0], sf[0][1]), fmaxf(sf[0][2], sf[0][3]));
    float h1 = fmaxf(fmaxf(sf[1][0], sf[1][1]), fmaxf(sf[1][2], sf[1][3]));
    float h2 = fmaxf(fmaxf(sf[2][0], sf[2][1]), fmaxf(sf[2][2], sf[2][3]));
    float h3 = fmaxf(fmaxf(sf[3][0], sf[3][1]), fmaxf(sf[3][2], sf[3][3]));
    float pm = fmaxf(fmaxf(h0, h1), fmaxf(h2, h3));
    pm = fmaxf(pm, __shfl_xor(pm, 16, 64));
    pm = fmaxf(pm, __shfl_xor(pm, 32, 64));
    const float pmax_abs = pm + ktf + bmax;

    if (!__all(pmax_abs - mrun <= 8.f)) {
      const float mnew = fmaxf(mrun, pmax_abs);
      const float scl = exp2f(mrun - mnew);
      mrun = mnew;
#pragma unroll
      for (int r = 0; r < 4; ++r) {
        const float sr = __shfl(scl, 4 * lhi + r, 64);
        lrun[r] *= sr;
#pragma unroll
        for (int hf = 0; hf < 4; ++hf) o[hf][r] *= sr;
      }
    }
    const float meff = mrun - ktf;

#pragma unroll
    for (int jf = 0; jf < 4; ++jf) {
      f32x4 pp;
#pragma unroll
      for (int r = 0; r < 4; ++r)
        pp[r] = exp2f(sf[jf][r] + (be[jf][r] - meff));
      u32x2 pw2;
      pw2[0] = cvtpk(pp[0], pp[1]);
      pw2[1] = cvtpk(pp[2], pp[3]);
      const int u = (2 * jf + (lhi >> 1)) ^ c7;
      *(u32x2*)&Pw[l15 * 64 + u * 8 + (lhi & 1) * 4] = pw2;
    }

    bf16x8 pa0 = *(const bf16x8*)&Pw[l15 * 64 + ((lhi ^ c7) * 8)];
    bf16x8 pa1 = *(const bf16x8*)&Pw[l15 * 64 + (((4 + lhi) ^ c7) * 8)];
    f32x4 psum = {};
    __builtin_amdgcn_s_setprio(1);
    psum = MFMA16(pa0, vones, psum, 0, 0, 0);
    psum = MFMA16(pa1, vones, psum, 0, 0, 0);
#pragma unroll
    for (int hf = 0; hf < 4; ++hf) {
      o[hf] = MFMA16(pa0, vf[2 * hf], o[hf], 0, 0, 0);
      o[hf] = MFMA16(pa1, vf[2 * hf + 1], o[hf], 0, 0, 0);
    }
    __builtin_amdgcn_s_setprio(0);
    lrun += psum;
  };

  for (int t = 0; t < ntB; ++t) {
    const int cb = t & 3;
    if (t + 2 < ntB) {
      const int sb = (t + 2) & 3;
      gl_lds16(kst, &Ks[sb][tid * 8]);
      gl_lds16(kst + 32 * HD, &Ks[sb][2048 + tid * 8]);
      gl_lds16(vst, &Vs[sb][tid * 8]);
      gl_lds16(vst + (long)32 * T_LEN, &Vs[sb][2048 + tid * 8]);
      kst += 64 * HD;
      vst += 64;
    }
    const bool actA = (t < ntA);

    // K fragments once, shared by both q-sets
    bf16x8 kf[8];
#pragma unroll
    for (int jf = 0; jf < 4; ++jf) {
      const int krow = jf * 16 + l15;
      kf[2 * jf] = *(const bf16x8*)&Ks[cb][krow * 64 + ((lhi ^ c7) * 8)];
      kf[2 * jf + 1] = *(const bf16x8*)&Ks[cb][krow * 64 + (((4 + lhi) ^ c7) * 8)];
    }
    // V fragments once, shared by both q-sets
    bf16x8 vf[8];
#pragma unroll
    for (int hf = 0; hf < 4; ++hf) {
      const int vrow = hf * 16 + l15;
      vf[2 * hf] = *(const bf16x8*)&Vs[cb][vrow * 64 + ((lhi ^ c7) * 8)];
      vf[2 * hf + 1] = *(const bf16x8*)&Vs[cb][vrow * 64 + (((4 + lhi) ^ c7) * 8)];
    }

    // QK^T for both q-sets
    f32x4 sB[4], sA[4];
    __builtin_amdgcn_s_setprio(1);
#pragma unroll
    for (int jf = 0; jf < 4; ++jf) {
      f32x4 s = {};
      s = MFMA16(kf[2 * jf], aqB0, s, 0, 0, 0);
      s = MFMA16(kf[2 * jf + 1], aqB1, s, 0, 0, 0);
      sB[jf] = s;
    }
    __builtin_amdgcn_s_setprio(0);
    if (actA) {
      __builtin_amdgcn_s_setprio(1);
#pragma unroll
      for (int jf = 0; jf < 4; ++jf) {
        f32x4 s = {};
        s = MFMA16(kf[2 * jf], aqA0, s, 0, 0, 0);
        s = MFMA16(kf[2 * jf + 1], aqA1, s, 0, 0, 0);
        sA[jf] = s;
      }
      __builtin_amdgcn_s_setprio(0);
    }

    process(sB, t == ntB - 1, oB, lrunB, mrunB, vf, &Ps[0][wv][0]);
    if (actA) process(sA, t == ntA - 1, oA, lrunA, mrunA, vf, &Ps[1][wv][0]);

    ktf += kstep;
    if ((t & 1) && (t + 1 < ntB)) __syncthreads();
  }

  // epilogue: rows q_local = 4*lhi + r; cols hd = hf*16 + l15
#pragma unroll
  for (int r = 0; r < 4; ++r) {
    const float invA = 1.f / lrunA[r];
    const float invB = 1.f / lrunB[r];
    const long rowA = (long)b * S_LEN + qA0 + wv * 16 + 4 * lhi + r;
    const long rowB = (long)b * S_LEN + qB0 + wv * 16 + 4 * lhi + r;
#pragma unroll
    for (int hf = 0; hf < 4; ++hf) {
      ctx[rowA * DIM + h * HD + hf * 16 + l15] = f2bf(oA[hf][r] * invA);
      ctx[rowB * DIM + h * HD + hf * 16 + l15] = f2bf(oB[hf][r] * invB);
    }
  }
}

// ---------------------------------------------------------------------------
extern "C" void kernel_launch(void* const* d_in, const int* in_sizes, int n_in,
                              void* d_out, int out_size, void* d_ws, size_t ws_size,
                              hipStream_t stream) {
  (void)in_sizes; (void)n_in; (void)out_size; (void)ws_size;
  const float* x       = (const float*)d_in[0];
  const float* cache_k = (const float*)d_in[1];
  const float* cache_v = (const float*)d_in[2];
  const float* cosT    = (const float*)d_in[3];
  const float* sinT    = (const float*)d_in[4];
  const float* attn_w  = (const float*)d_in[5];
  const float* ffn_w   = (const float*)d_in[6];
  const float* wq      = (const float*)d_in[7];
  const float* bq      = (const float*)d_in[8];
  const float* wk      = (const float*)d_in[9];
  const float* bk      = (const float*)d_in[10];
  const float* wv_     = (const float*)d_in[11];
  const float* bv      = (const float*)d_in[12];
  const float* wo      = (const float*)d_in[13];
  const float* bo      = (const float*)d_in[14];
  const float* wg      = (const float*)d_in[15];
  const float* bg      = (const float*)d_in[16];
  const float* wval    = (const float*)d_in[17];
  const float* bval    = (const float*)d_in[18];
  const float* wp      = (const float*)d_in[19];
  const float* bp      = (const float*)d_in[20];
  float* out = (float*)d_out;

  char* w = (char*)d_ws;
  size_t off = 0;
  auto alloc = [&](size_t bytes) -> char* {
    char* p = w + off;
    off += (bytes + 255) & ~(size_t)255;
    return p;
  };
  // permanent
  u16*   wqkv_bf  = (u16*)alloc((size_t)3 * DIM * DIM * 2);  // preswizzled
  u16*   wo_bf    = (u16*)alloc((size_t)DIM * DIM * 2);      // linear
  u16*   wgv_bf   = (u16*)alloc((size_t)2 * FF * DIM * 2);   // interleaved+preswizzled
  u16*   wproj_bf = (u16*)alloc((size_t)DIM * FF * 2);       // linear
  float* bqkv     = (float*)alloc((size_t)3 * DIM * 4);
  float* bgv      = (float*)alloc((size_t)2 * FF * 4);       // interleaved
  float* x2       = (float*)alloc((size_t)MROWS * DIM * 4);
  // arena with lifetime-based aliasing
  char* AR = alloc((size_t)117440512);
  u16* qkv   = (u16*)(AR + 0);          // [4096][3072]   live: qkv gemm -> rope/build
  u16* Qb    = (u16*)(AR + 25165824);   // [32][2048][64] live: rope -> attn
  u16* Kb    = (u16*)(AR + 33554432);   // [32][3072][64]
  u16* Vtg   = (u16*)(AR + 46137344);   // [32][64][3072] transposed V
  u16* h1    = (u16*)(AR + 58720256);   // [4096][1024]   preswizzled (qkv gemm A)
  u16* ctx   = (u16*)(AR + 0);          // [4096][1024]   linear (aliases dead qkv)
  u16* h2    = (u16*)(AR + 8388608);    // [4096][1024]   preswizzled (gv gemm A)
  u16* gated = (u16*)(AR + 16777216);   // [4096][4096]   linear

  // 1) ALL weight + bias conversion in one launch
  cvt_all_kernel<<<6172, 256, 0, stream>>>(wq, wk, wv_, wg, wval, wo, wp,
                                           bq, bk, bv, bg, bval,
                                           wqkv_bf, wgv_bf, wo_bf, wproj_bf,
                                           bqkv, bgv);

  // 2) attn rmsnorm (swizzled out), fused QKV 256-gemm
  rmsnorm_kernel<<<MROWS, 256, 0, stream>>>(x, attn_w, h1);
  gemm256<0><<<dim3(12, 16), 512, 0, stream>>>(h1, wqkv_bf, bqkv, qkv, 3 * DIM, DIM);
  // 3) fused rope + cache concat (1 launch)
  rope_all_kernel<<<8192, 256, 0, stream>>>(qkv, cache_k, cache_v, cosT, sinT,
                                            Qb, Kb, Vtg);
  // 4) attention: paired dual-Q blocks, 4-buffer KV, half the barriers
  attn_kernel<<<dim3(B_SZ * NH, 16), 256, 0, stream>>>(
      Qb, Kb, Vtg, ctx, (2.0f / (float)(T_LEN - 1)) * LOG2E);
  // 5) o-proj + residual (fp32), skinny tile
  gemm_bt<1, 64><<<dim3(16, 32), 256, 0, stream>>>(ctx, wo_bf, bo, x, nullptr, x2,
                                                   DIM, DIM);
  // 6) ffn rmsnorm (swizzled out), gate+value 256-gemm w/ silu epilogue, proj + residual
  rmsnorm_kernel<<<MROWS, 256, 0, stream>>>(x2, ffn_w, h2);
  gemm256<2><<<dim3(32, 16), 512, 0, stream>>>(h2, wgv_bf, bgv, gated, 2 * FF, DIM);
  gemm_bt<1, 64><<<dim3(16, 32), 256, 0, stream>>>(gated, wproj_bf, bp, x2, nullptr, out,
                                                   DIM, FF);
}